// Round 3
// baseline (393.711 us; speedup 1.0000x reference)
//
#include <hip/hip_runtime.h>
#include <stdint.h>

typedef unsigned short u16;
typedef unsigned char u8;
typedef __attribute__((ext_vector_type(8))) short short8x;
typedef __attribute__((ext_vector_type(4))) float f32x4;

#define DEV static __device__ __forceinline__

DEV u16 f2bf(float f) {
  union { float f; unsigned u; } v; v.f = f;
  unsigned r = v.u + 0x7FFFu + ((v.u >> 16) & 1u);
  return (u16)(r >> 16);
}
DEV int imin(int a, int b) { return a < b ? a : b; }
DEV int imax(int a, int b) { return a > b ? a : b; }

DEV float ex2(float x) {
#if __has_builtin(__builtin_amdgcn_exp2f)
  return __builtin_amdgcn_exp2f(x);
#else
  return exp2f(x);
#endif
}

DEV void gload16(const void* g, void* l) {
  __builtin_amdgcn_global_load_lds((const __attribute__((address_space(1))) void*)g,
                                   (__attribute__((address_space(3))) void*)l, 16, 0, 0);
}

#define LOG2E 1.44269504f

// ---------------------------------------------------------------------------
// Weight convert+transpose: w[k][n] fp32 -> wt[mat][n][k] bf16 (7 mats)
struct WPtrs { const float* p[7]; };

__global__ __launch_bounds__(256) void wconv_kernel(WPtrs wp, u16* __restrict__ wt) {
  const int mat = blockIdx.y;
  const int kt = blockIdx.x % 12, nt = blockIdx.x / 12;
  const float* __restrict__ w = wp.p[mat];
  __shared__ float tile[64][72];
  const int t = threadIdx.x;
  {
    const int kk = t >> 2, n0 = (t & 3) * 16;
    const float* src = w + (size_t)(kt * 64 + kk) * 768 + nt * 64 + n0;
#pragma unroll
    for (int i = 0; i < 4; ++i)
      *(float4*)&tile[kk][n0 + i * 4] = *(const float4*)(src + i * 4);
  }
  __syncthreads();
  {
    const int nn = t >> 2, k0 = (t & 3) * 16;
    u16* dst = wt + (size_t)(mat * 768 + nt * 64 + nn) * 768 + kt * 64 + k0;
    short8x v0, v1;
#pragma unroll
    for (int j = 0; j < 8; ++j) {
      v0[j] = (short)f2bf(tile[k0 + j][nn]);
      v1[j] = (short)f2bf(tile[k0 + 8 + j][nn]);
    }
    *(short8x*)dst = v0;
    *(short8x*)(dst + 8) = v1;
  }
}

// ---------------------------------------------------------------------------
// h = emb[x] + pos  -> bf16  (8192 x 768)
__global__ __launch_bounds__(256) void embed_kernel(const int* __restrict__ x, const float* __restrict__ emb,
                                                    const float* __restrict__ pos, u16* __restrict__ hb) {
  const int n4 = 2 * 4096 * 192;
  for (int i = blockIdx.x * 256 + threadIdx.x; i < n4; i += gridDim.x * 256) {
    const int r = i / 192;
    const int d4 = i - r * 192;
    const int s = r & 4095;
    const int tok = x[r];
    const float4 e = *(const float4*)(emb + (size_t)tok * 768 + d4 * 4);
    const float4 p = *(const float4*)(pos + (size_t)s * 768 + d4 * 4);
    union { u16 u[4]; uint2 v; } o;
    o.u[0] = f2bf(e.x + p.x);
    o.u[1] = f2bf(e.y + p.y);
    o.u[2] = f2bf(e.z + p.z);
    o.u[3] = f2bf(e.w + p.w);
    *(uint2*)(hb + (size_t)r * 768 + d4 * 4) = o.v;
  }
}

// ---------------------------------------------------------------------------
// isg (global-token flags) + kval[b][key] = mask && !isg  (band-key validity)
__global__ __launch_bounds__(256) void isg_kernel(const int* __restrict__ clss, const int* __restrict__ mask,
                                                  u8* __restrict__ isg, u8* __restrict__ kval) {
  const int t = threadIdx.x;
  for (int i = t; i < 4096; i += 256) isg[i] = 0;
  __syncthreads();
  if (t < 64) isg[clss[t]] = 1;
  __syncthreads();
  for (int b = 0; b < 2; ++b)
    for (int i = t; i < 4096; i += 256)
      kval[b * 4096 + i] = (u8)((mask[b * 4096 + i] != 0) & (isg[i] == 0));
}

// ---------------------------------------------------------------------------
// 128x128x32 bf16 MFMA GEMM, B pre-transposed (N x K), global_load_lds staging.
// MODE 0: A=h (8192x768), Bt=Wt cat (4608x768): write q,k,v,kg,vg,qg in (B,H,S,DH) bf16
//         q and qg scaled by DH^-0.5 * log2(e)  (softmax uses exp2)
// MODE 1: A=attn_out bf16 (8192x768), Bt=woT: write fp32 d_out row-major
struct Outs6 { u16* p[6]; };

template <int MODE>
__global__ __launch_bounds__(256) void gemm_kernel(const u16* __restrict__ A, const u16* __restrict__ Bt,
                                                   Outs6 outs, float* __restrict__ outF) {
  __shared__ __align__(16) u16 smA[128 * 32];
  __shared__ __align__(16) u16 smB[128 * 32];
  const int t = threadIdx.x;
  const int l = t & 63, w = t >> 6;
  const int l15 = l & 15, grp = l >> 4;
  const int wm = w >> 1, wn = w & 1;
  const int m0 = blockIdx.y * 128, n0 = blockIdx.x * 128;
  const f32x4 zero4 = {0.f, 0.f, 0.f, 0.f};
  f32x4 acc[4][4];
#pragma unroll
  for (int mi = 0; mi < 4; ++mi)
#pragma unroll
    for (int ni = 0; ni < 4; ++ni) acc[mi][ni] = zero4;

  const int srow = w * 32 + (l >> 2);
  const int scol = (l & 3) * 8;
  const u16* gA = A + (size_t)(m0 + srow) * 768 + scol;
  const u16* gB = Bt + (size_t)(n0 + srow) * 768 + scol;
  u16* lA = smA + w * 1024;
  u16* lB = smB + w * 1024;

  for (int kb = 0; kb < 24; ++kb) {
    __syncthreads();
    const size_t ko = (size_t)kb * 32;
    gload16(gA + ko, lA);
    gload16(gA + 16 * 768 + ko, lA + 512);
    gload16(gB + ko, lB);
    gload16(gB + 16 * 768 + ko, lB + 512);
    __syncthreads();
    short8x af[4], bfr[4];
#pragma unroll
    for (int mi = 0; mi < 4; ++mi)
      af[mi] = *(const short8x*)(smA + (wm * 64 + mi * 16 + l15) * 32 + grp * 8);
#pragma unroll
    for (int ni = 0; ni < 4; ++ni)
      bfr[ni] = *(const short8x*)(smB + (wn * 64 + ni * 16 + l15) * 32 + grp * 8);
#pragma unroll
    for (int mi = 0; mi < 4; ++mi)
#pragma unroll
      for (int ni = 0; ni < 4; ++ni)
        acc[mi][ni] = __builtin_amdgcn_mfma_f32_16x16x32_bf16(af[mi], bfr[ni], acc[mi][ni], 0, 0, 0);
  }

  if (MODE == 0) {
    const int mat = blockIdx.x / 6;
    const int inn0 = n0 - mat * 768 + wn * 64;
    const float scl = (mat == 0 || mat == 5) ? 0.125f * LOG2E : 1.0f;
    u16* __restrict__ base = outs.p[mat];
#pragma unroll
    for (int mi = 0; mi < 4; ++mi)
#pragma unroll
      for (int ni = 0; ni < 4; ++ni) {
        const int col = inn0 + ni * 16 + l15;
        const int hd = col >> 6, dh = col & 63;
#pragma unroll
        for (int rr = 0; rr < 4; ++rr) {
          const int row = m0 + wm * 64 + mi * 16 + grp * 4 + rr;
          const int b = row >> 12, s = row & 4095;
          base[((size_t)(b * 12 + hd) * 4096 + s) * 64 + dh] = f2bf(acc[mi][ni][rr] * scl);
        }
      }
  } else {
#pragma unroll
    for (int mi = 0; mi < 4; ++mi)
#pragma unroll
      for (int rr = 0; rr < 4; ++rr) {
        const int row = m0 + wm * 64 + mi * 16 + grp * 4 + rr;
#pragma unroll
        for (int ni = 0; ni < 4; ++ni) {
          const int col = n0 + wn * 64 + ni * 16 + l15;
          outF[(size_t)row * 768 + col] = acc[mi][ni][rr];
        }
      }
  }
}

// ---------------------------------------------------------------------------
// (B,H,S,DH) -> (B,H,DH,S) bf16, two buffers (v->vT, vg->vgT)
__global__ __launch_bounds__(256) void transp_kernel(const u16* __restrict__ in0, u16* __restrict__ out0,
                                                     const u16* __restrict__ in1, u16* __restrict__ out1) {
  const u16* src = blockIdx.y ? in1 : in0;
  u16* dst = blockIdx.y ? out1 : out0;
  const int bh = blockIdx.x >> 6;
  const int s0 = (blockIdx.x & 63) << 6;
  __shared__ u16 tile[64][80];
  const int t = threadIdx.x;
  {
    const int sl = t >> 2, d0 = (t & 3) * 16;
    const u16* p = src + ((size_t)bh * 4096 + s0 + sl) * 64 + d0;
    *(short8x*)&tile[sl][d0] = *(const short8x*)p;
    *(short8x*)&tile[sl][d0 + 8] = *(const short8x*)(p + 8);
  }
  __syncthreads();
  {
    const int dh = t >> 2, q0 = (t & 3) * 16;
    short8x v0, v1;
#pragma unroll
    for (int j = 0; j < 8; ++j) {
      v0[j] = (short)tile[q0 + j][dh];
      v1[j] = (short)tile[q0 + 8 + j][dh];
    }
    u16* o = dst + ((size_t)bh * 64 + dh) * 4096 + s0 + q0;
    *(short8x*)o = v0;
    *(short8x*)(o + 8) = v1;
  }
}

// ---------------------------------------------------------------------------
// Gather K rows at clss -> kcls[bh][g][dh]; v rows at clss transposed -> vtcls[bh][dh][g]; mask at clss.
__global__ __launch_bounds__(256) void gcls_kernel(const u16* __restrict__ kB, const u16* __restrict__ vB,
                                                   const int* __restrict__ clss, const int* __restrict__ mask,
                                                   u16* __restrict__ kcls, u16* __restrict__ vtcls,
                                                   u8* __restrict__ mcls) {
  const int bh = blockIdx.x;
  const int b = bh / 12;
  __shared__ u16 tile[64][80];
  const int t = threadIdx.x;
  {
    const int g = t >> 2, d0 = (t & 3) * 16;
    const int row = clss[g];
    const u16* pk = kB + ((size_t)bh * 4096 + row) * 64 + d0;
    u16* ok = kcls + ((size_t)bh * 64 + g) * 64 + d0;
    *(short8x*)ok = *(const short8x*)pk;
    *(short8x*)(ok + 8) = *(const short8x*)(pk + 8);
    const u16* pv = vB + ((size_t)bh * 4096 + row) * 64 + d0;
    *(short8x*)&tile[g][d0] = *(const short8x*)pv;
    *(short8x*)&tile[g][d0 + 8] = *(const short8x*)(pv + 8);
  }
  if (t < 64) mcls[b * 64 + t] = (mask[(size_t)b * 4096 + clss[t]] != 0) ? 1 : 0;
  __syncthreads();
  {
    const int dh = t >> 2, g0 = (t & 3) * 16;
    short8x v0, v1;
#pragma unroll
    for (int j = 0; j < 8; ++j) {
      v0[j] = (short)tile[g0 + j][dh];
      v1[j] = (short)tile[g0 + 8 + j][dh];
    }
    u16* o = vtcls + ((size_t)bh * 64 + dh) * 64 + g0;
    *(short8x*)o = v0;
    *(short8x*)(o + 8) = v1;
  }
}

// ---------------------------------------------------------------------------
// Band + global-key attention. 768 blocks of 128 queries (4 waves x 32q).
// K/V^T tiles staged block-wide into LDS via global_load_lds, double-buffered
// 2-phase prefetch. Source-pre-swizzled (seg ^ row&7) so reads are conflict-free.
__global__ __launch_bounds__(256, 3) void band_kernel(
    const u16* __restrict__ qB, const u16* __restrict__ kB, const u16* __restrict__ vT,
    const u16* __restrict__ kcls, const u16* __restrict__ vtcls, const u8* __restrict__ mcls,
    const u8* __restrict__ kval, u16* __restrict__ aout) {
  int bid = blockIdx.x;
  bid = (bid & 7) * 96 + (bid >> 3);   // XCD chunking (768 = 8 * 96, bijective)
  const int qblk = bid & 31;
  const int h = (bid >> 5) % 12;
  const int b = bid / 384;
  const int t = threadIdx.x;
  const int w = t >> 6, l = t & 63, l15 = l & 15, grp = l >> 4;
  const int bh = b * 12 + h;
  const int q0b = qblk * 128;
  const int q0 = q0b + w * 32;

  __shared__ __align__(16) u16 Kl[2][4096];   // 64 keys x 64 dh, swizzled rows
  __shared__ __align__(16) u16 Vl[2][4096];   // 64 dh x 64 keys, swizzled rows
  __shared__ __align__(16) u16 Pt[4][2048];   // per-wave 32x64 P, XOR-swizzled
  __shared__ u8 sKval[640];
  __shared__ u8 sMcls[64];

  const int tloB = imax(0, (q0b - 256) >> 6);
  const int thiB = imin(63, (q0b + 383) >> 6);
  const int nB = thiB - tloB + 1;                       // <= 10 band tiles

  const u16* kbh = kB + (size_t)bh * 4096 * 64;
  const u16* vbh = vT + (size_t)bh * 64 * 4096;
  const u16* kcb = kcls + (size_t)bh * 4096;
  const u16* vcb = vtcls + (size_t)bh * 4096;
  const u8* kvb = kval + b * 4096;

  for (int i = t; i < nB * 64; i += 256) sKval[i] = kvb[tloB * 64 + i];
  if (t < 64) sMcls[t] = mcls[b * 64 + t];

  // wave-active band tile range (relative to tloB)
  const int tlo_w = (imax(0, (q0 - 256) >> 6)) - tloB;
  const int thi_w = (imin(63, (q0 + 287) >> 6)) - tloB;

  // stage tile into LDS buf: K rows=keys, V rows=dh; both 64 rows x 128B.
  // linear LDS dest + inverse-swizzled global source (rule: both-sides-or-neither).
  auto STAGE = [&](const u16* ksrc, const u16* vsrc, int vstride, int buf) {
#pragma unroll
    for (int c = 0; c < 2; ++c) {
      const int rw = w + 4 * c;
      const int row = rw * 8 + (l >> 3);
      const int seg = (l & 7) ^ (row & 7);
      gload16(ksrc + row * 64 + seg * 8, (char*)Kl[buf] + rw * 1024);
      gload16(vsrc + (size_t)row * vstride + seg * 8, (char*)Vl[buf] + rw * 1024);
    }
  };

  // q fragments
  const u16* qb = qB + ((size_t)bh * 4096 + q0) * 64;
  short8x qf[2][2];
#pragma unroll
  for (int qi = 0; qi < 2; ++qi)
#pragma unroll
    for (int ks = 0; ks < 2; ++ks)
      qf[qi][ks] = *(const short8x*)(qb + (qi * 16 + l15) * 64 + ks * 32 + grp * 8);

  const f32x4 zero4 = {0.f, 0.f, 0.f, 0.f};
  f32x4 accD[2][4];
  float mst[2][4], lst[2][4];
#pragma unroll
  for (int qi = 0; qi < 2; ++qi)
#pragma unroll
    for (int j = 0; j < 4; ++j) { accD[qi][j] = zero4; mst[qi][j] = -60.f; lst[qi][j] = 0.f; }

  // prologue: stage tile 0
  STAGE(kbh + (size_t)tloB * 64 * 64, vbh + (size_t)tloB * 64, 4096, 0);
  asm volatile("s_waitcnt vmcnt(0)" ::: "memory");
  __syncthreads();

  for (int i = 0; i <= nB; ++i) {
    const int buf = i & 1;
    // prefetch next tile (band i+1, or the global tile at i+1==nB)
    if (i < nB) {
      if (i + 1 == nB) STAGE(kcb, vcb, 64, buf ^ 1);
      else             STAGE(kbh + (size_t)(tloB + i + 1) * 64 * 64,
                             vbh + (size_t)(tloB + i + 1) * 64, 4096, buf ^ 1);
    }
    const bool isG = (i == nB);
    if (isG || (i >= tlo_w && i <= thi_w)) {
      const int kbase = (tloB + i) * 64;
      int kok[4];
#pragma unroll
      for (int kj = 0; kj < 4; ++kj)
        kok[kj] = isG ? sMcls[kj * 16 + l15] : sKval[i * 64 + kj * 16 + l15];

      // QK^T from LDS (swizzled reads)
      f32x4 sf[2][4];
#pragma unroll
      for (int qi = 0; qi < 2; ++qi)
#pragma unroll
        for (int kj = 0; kj < 4; ++kj) sf[qi][kj] = zero4;
#pragma unroll
      for (int ks = 0; ks < 2; ++ks) {
        short8x kfk[4];
#pragma unroll
        for (int kj = 0; kj < 4; ++kj) {
          const int key = kj * 16 + l15;
          const int byo = key * 128 + ((ks * 64 + grp * 16) ^ ((key & 7) << 4));
          kfk[kj] = *(const short8x*)((const char*)Kl[buf] + byo);
        }
#pragma unroll
        for (int qi = 0; qi < 2; ++qi)
#pragma unroll
          for (int kj = 0; kj < 4; ++kj)
            sf[qi][kj] = __builtin_amdgcn_mfma_f32_16x16x32_bf16(qf[qi][ks], kfk[kj], sf[qi][kj], 0, 0, 0);
      }

      // mask + row-max
      float tmr[2][4];
#pragma unroll
      for (int qi = 0; qi < 2; ++qi) {
        const int qr0 = q0 + qi * 16 + grp * 4;
        float tm[4];
#pragma unroll
        for (int rr = 0; rr < 4; ++rr) tm[rr] = -1e30f;
#pragma unroll
        for (int kj = 0; kj < 4; ++kj)
#pragma unroll
          for (int rr = 0; rr < 4; ++rr) {
            int valid = kok[kj];
            if (!isG) {
              const int rel = kbase + kj * 16 + l15 - (qr0 + rr);
              valid = valid & (int)(rel >= -256) & (int)(rel <= 256);
            }
            const float sv = valid ? sf[qi][kj][rr] : -1e30f;
            sf[qi][kj][rr] = sv;
            tm[rr] = fmaxf(tm[rr], sv);
          }
#pragma unroll
        for (int rr = 0; rr < 4; ++rr) {
          float v = tm[rr];
          v = fmaxf(v, __shfl_xor(v, 1));
          v = fmaxf(v, __shfl_xor(v, 2));
          v = fmaxf(v, __shfl_xor(v, 4));
          v = fmaxf(v, __shfl_xor(v, 8));
          tmr[qi][rr] = v;
        }
      }

      // defer-max: wave-uniform skip of the rescale when growth <= 8 (log2 units)
      int lok = 1;
#pragma unroll
      for (int qi = 0; qi < 2; ++qi)
#pragma unroll
        for (int rr = 0; rr < 4; ++rr) lok &= (int)(tmr[qi][rr] <= mst[qi][rr] + 8.f);
      if (__all(lok)) {
#pragma unroll
        for (int qi = 0; qi < 2; ++qi)
#pragma unroll
          for (int rr = 0; rr < 4; ++rr) {
            const float mo = mst[qi][rr];
            float ps = 0.f;
#pragma unroll
            for (int kj = 0; kj < 4; ++kj) {
              const float p = ex2(sf[qi][kj][rr] - mo);
              sf[qi][kj][rr] = p;
              ps += p;
            }
            ps += __shfl_xor(ps, 1);
            ps += __shfl_xor(ps, 2);
            ps += __shfl_xor(ps, 4);
            ps += __shfl_xor(ps, 8);
            lst[qi][rr] += ps;
          }
      } else {
#pragma unroll
        for (int qi = 0; qi < 2; ++qi)
#pragma unroll
          for (int rr = 0; rr < 4; ++rr) {
            const float mo = mst[qi][rr];
            const float mn = fmaxf(mo, tmr[qi][rr]);
            const float sc = ex2(mo - mn);
            float ps = 0.f;
#pragma unroll
            for (int kj = 0; kj < 4; ++kj) {
              const float p = ex2(sf[qi][kj][rr] - mn);
              sf[qi][kj][rr] = p;
              ps += p;
            }
            ps += __shfl_xor(ps, 1);
            ps += __shfl_xor(ps, 2);
            ps += __shfl_xor(ps, 4);
            ps += __shfl_xor(ps, 8);
            lst[qi][rr] = lst[qi][rr] * sc + ps;
            mst[qi][rr] = mn;
#pragma unroll
            for (int dj = 0; dj < 4; ++dj) accD[qi][dj][rr] *= sc;
          }
      }

      // P -> LDS bf16 (row*128B + key*2B, XOR swizzle bits 4-6 by row&7)
      u16* P = Pt[w];
#pragma unroll
      for (int qi = 0; qi < 2; ++qi)
#pragma unroll
        for (int rr = 0; rr < 4; ++rr) {
          const int ql = qi * 16 + grp * 4 + rr;
          const int swz = (ql & 7) << 4;
          char* rowp = (char*)P + ql * 128;
#pragma unroll
          for (int kj = 0; kj < 4; ++kj) {
            const int byo = ((kj * 16 + l15) * 2) ^ swz;
            *(u16*)(rowp + byo) = f2bf(sf[qi][kj][rr]);
          }
        }
      asm volatile("s_waitcnt lgkmcnt(0)" ::: "memory");
      __builtin_amdgcn_sched_barrier(0);

      // PV: A = P (LDS), B = V^T tile (LDS, swizzled reads)
#pragma unroll
      for (int ks = 0; ks < 2; ++ks) {
        short8x pak[2], vfk[4];
#pragma unroll
        for (int qi = 0; qi < 2; ++qi) {
          const int ql = qi * 16 + l15;
          const int byo = (ql * 128 + ks * 64 + grp * 16) ^ ((ql & 7) << 4);
          pak[qi] = *(const short8x*)((const char*)P + byo);
        }
#pragma unroll
        for (int dj = 0; dj < 4; ++dj) {
          const int dh = dj * 16 + l15;
          const int byo = dh * 128 + ((ks * 64 + grp * 16) ^ ((dh & 7) << 4));
          vfk[dj] = *(const short8x*)((const char*)Vl[buf] + byo);
        }
#pragma unroll
        for (int qi = 0; qi < 2; ++qi)
#pragma unroll
          for (int dj = 0; dj < 4; ++dj)
            accD[qi][dj] = __builtin_amdgcn_mfma_f32_16x16x32_bf16(pak[qi], vfk[dj], accD[qi][dj], 0, 0, 0);
      }
      asm volatile("s_waitcnt lgkmcnt(0)" ::: "memory");  // P reads done before next-tile P writes
      __builtin_amdgcn_sched_barrier(0);
    }
    asm volatile("s_waitcnt vmcnt(0)" ::: "memory");
    __syncthreads();
  }

  // finalize: divide by row sums, store (B,S,D) bf16
  u16* ob = aout + ((size_t)b * 4096 + q0) * 768 + h * 64;
#pragma unroll
  for (int qi = 0; qi < 2; ++qi)
#pragma unroll
    for (int rr = 0; rr < 4; ++rr) {
      const float inv = 1.f / lst[qi][rr];
      const int row = qi * 16 + grp * 4 + rr;
#pragma unroll
      for (int dj = 0; dj < 4; ++dj)
        ob[(size_t)row * 768 + dj * 16 + l15] = f2bf(accD[qi][dj][rr] * inv);
    }
}

// ---------------------------------------------------------------------------
// Global-token attention, part 1: one wave per (b,h,kslice); 8 key-tiles each.
__global__ __launch_bounds__(64) void ogp_kernel(
    const u16* __restrict__ qgB, const u16* __restrict__ kgB, const u16* __restrict__ vgT,
    const int* __restrict__ clss, const int* __restrict__ mask,
    float* __restrict__ pm, float* __restrict__ pl, float* __restrict__ pacc) {
  const int blk = blockIdx.x;  // bh*8 + slice
  const int bh = blk >> 3, sl = blk & 7;
  const int b = bh / 12;
  const int l = threadIdx.x, l15 = l & 15, grp = l >> 4;

  __shared__ u16 P[4096];

  const u16* qgb = qgB + (size_t)bh * 4096 * 64;
  const u16* kgb = kgB + (size_t)bh * 4096 * 64;
  const u16* vgb = vgT + (size_t)bh * 64 * 4096;

  short8x qf[4][2];
#pragma unroll
  for (int qi = 0; qi < 4; ++qi) {
    const int srow = clss[qi * 16 + l15];
    qf[qi][0] = *(const short8x*)(qgb + (size_t)srow * 64 + grp * 8);
    qf[qi][1] = *(const short8x*)(qgb + (size_t)srow * 64 + 32 + grp * 8);
  }

  const f32x4 zero4 = {0.f, 0.f, 0.f, 0.f};
  f32x4 accD[4][4];
  float mst[4][4], lst[4][4];
#pragma unroll
  for (int qi = 0; qi < 4; ++qi)
#pragma unroll
    for (int j = 0; j < 4; ++j) { accD[qi][j] = zero4; mst[qi][j] = -60.f; lst[qi][j] = 0.f; }

  for (int tt = sl * 8; tt < sl * 8 + 8; ++tt) {
    const int kbase = tt * 64;
    int kok[4];
    f32x4 sf[4][4];
#pragma unroll
    for (int kj = 0; kj < 4; ++kj) {
      kok[kj] = (mask[b * 4096 + kbase + kj * 16 + l15] != 0);
#pragma unroll
      for (int qi = 0; qi < 4; ++qi) sf[qi][kj] = zero4;
    }
#pragma unroll
    for (int ks = 0; ks < 2; ++ks) {
      short8x kfk[4];
#pragma unroll
      for (int kj = 0; kj < 4; ++kj)
        kfk[kj] = *(const short8x*)(kgb + (size_t)(kbase + kj * 16 + l15) * 64 + ks * 32 + grp * 8);
#pragma unroll
      for (int qi = 0; qi < 4; ++qi)
#pragma unroll
        for (int kj = 0; kj < 4; ++kj)
          sf[qi][kj] = __builtin_amdgcn_mfma_f32_16x16x32_bf16(qf[qi][ks], kfk[kj], sf[qi][kj], 0, 0, 0);
    }
#pragma unroll
    for (int qi = 0; qi < 4; ++qi) {
      float tm[4];
#pragma unroll
      for (int rr = 0; rr < 4; ++rr) tm[rr] = -1e30f;
#pragma unroll
      for (int kj = 0; kj < 4; ++kj)
#pragma unroll
        for (int rr = 0; rr < 4; ++rr) {
          const float sv = kok[kj] ? sf[qi][kj][rr] : -1e30f;
          sf[qi][kj][rr] = sv;
          tm[rr] = fmaxf(tm[rr], sv);
        }
#pragma unroll
      for (int rr = 0; rr < 4; ++rr) {
        float v = tm[rr];
        v = fmaxf(v, __shfl_xor(v, 1));
        v = fmaxf(v, __shfl_xor(v, 2));
        v = fmaxf(v, __shfl_xor(v, 4));
        v = fmaxf(v, __shfl_xor(v, 8));
        const float mo = mst[qi][rr];
        const float mn = fmaxf(mo, v);
        const float sc = ex2(mo - mn);
        float ps = 0.f;
#pragma unroll
        for (int kj = 0; kj < 4; ++kj) {
          const float p = ex2(sf[qi][kj][rr] - mn);
          sf[qi][kj][rr] = p;
          ps += p;
        }
        ps += __shfl_xor(ps, 1);
        ps += __shfl_xor(ps, 2);
        ps += __shfl_xor(ps, 4);
        ps += __shfl_xor(ps, 8);
        lst[qi][rr] = lst[qi][rr] * sc + ps;
        mst[qi][rr] = mn;
#pragma unroll
        for (int dj = 0; dj < 4; ++dj) accD[qi][dj][rr] *= sc;
      }
    }
#pragma unroll
    for (int qi = 0; qi < 4; ++qi)
#pragma unroll
      for (int rr = 0; rr < 4; ++rr) {
        const int ql = qi * 16 + grp * 4 + rr;
        const int swz = (ql & 7) << 4;
        char* rowp = (char*)P + ql * 128;
#pragma unroll
        for (int kj = 0; kj < 4; ++kj) {
          const int byo = ((kj * 16 + l15) * 2) ^ swz;
          *(u16*)(rowp + byo) = f2bf(sf[qi][kj][rr]);
        }
      }
    asm volatile("s_waitcnt lgkmcnt(0)" ::: "memory");
    __builtin_amdgcn_sched_barrier(0);
#pragma unroll
    for (int ks = 0; ks < 2; ++ks) {
      short8x pak[4], vfk[4];
#pragma unroll
      for (int qi = 0; qi < 4; ++qi) {
        const int ql = qi * 16 + l15;
        const int byo = (ql * 128 + ks * 64 + grp * 16) ^ ((ql & 7) << 4);
        pak[qi] = *(const short8x*)((const char*)P + byo);
      }
#pragma unroll
      for (int dj = 0; dj < 4; ++dj) {
        const int dh = dj * 16 + l15;
        vfk[dj] = *(const short8x*)(vgb + (size_t)dh * 4096 + kbase + ks * 32 + grp * 8);
      }
#pragma unroll
      for (int qi = 0; qi < 4; ++qi)
#pragma unroll
        for (int dj = 0; dj < 4; ++dj)
          accD[qi][dj] = __builtin_amdgcn_mfma_f32_16x16x32_bf16(pak[qi], vfk[dj], accD[qi][dj], 0, 0, 0);
    }
    asm volatile("s_waitcnt lgkmcnt(0)" ::: "memory");
    __builtin_amdgcn_sched_barrier(0);
  }

#pragma unroll
  for (int qi = 0; qi < 4; ++qi)
#pragma unroll
    for (int dj = 0; dj < 4; ++dj)
#pragma unroll
      for (int rr = 0; rr < 4; ++rr) {
        const int row = qi * 16 + grp * 4 + rr;
        pacc[(size_t)blk * 4096 + row * 64 + dj * 16 + l15] = accD[qi][dj][rr];
      }
  if (l15 == 0)
#pragma unroll
    for (int qi = 0; qi < 4; ++qi)
#pragma unroll
      for (int rr = 0; rr < 4; ++rr) {
        const int row = qi * 16 + grp * 4 + rr;
        pm[blk * 64 + row] = mst[qi][rr];
        pl[blk * 64 + row] = lst[qi][rr];
      }
}

// ---------------------------------------------------------------------------
// Global-token attention merge: combine 8 key-slice partials, overwrite clss rows of aout.
__global__ __launch_bounds__(256) void ogm_kernel(const float* __restrict__ pm, const float* __restrict__ pl,
                                                  const float* __restrict__ pacc, const int* __restrict__ clss,
                                                  u16* __restrict__ aout) {
  const int bh = blockIdx.x;
  const int b = bh / 12, h = bh % 12;
  const int t = threadIdx.x;
  const int r = t >> 2, cs = (t & 3) * 16;
  float mv[8];
  float M = -1e30f;
#pragma unroll
  for (int s = 0; s < 8; ++s) {
    mv[s] = pm[(bh * 8 + s) * 64 + r];
    M = fmaxf(M, mv[s]);
  }
  float L = 0.f, f[8];
#pragma unroll
  for (int s = 0; s < 8; ++s) {
    f[s] = ex2(mv[s] - M);
    L += pl[(bh * 8 + s) * 64 + r] * f[s];
  }
  float o[16];
#pragma unroll
  for (int j = 0; j < 16; ++j) o[j] = 0.f;
#pragma unroll
  for (int s = 0; s < 8; ++s) {
    const float* pr = pacc + (size_t)(bh * 8 + s) * 4096 + r * 64 + cs;
#pragma unroll
    for (int j4 = 0; j4 < 4; ++j4) {
      const float4 a = *(const float4*)(pr + j4 * 4);
      o[j4 * 4 + 0] += a.x * f[s];
      o[j4 * 4 + 1] += a.y * f[s];
      o[j4 * 4 + 2] += a.z * f[s];
      o[j4 * 4 + 3] += a.w * f[s];
    }
  }
  const float inv = 1.f / L;
  short8x v0, v1;
#pragma unroll
  for (int j = 0; j < 8; ++j) {
    v0[j] = (short)f2bf(o[j] * inv);
    v1[j] = (short)f2bf(o[8 + j] * inv);
  }
  u16* op = aout + ((size_t)b * 4096 + clss[r]) * 768 + h * 64 + cs;
  *(short8x*)op = v0;
  *(short8x*)(op + 8) = v1;
}

// ---------------------------------------------------------------------------
extern "C" void kernel_launch(void* const* d_in, const int* in_sizes, int n_in,
                              void* d_out, int out_size, void* d_ws, size_t ws_size,
                              hipStream_t stream) {
  (void)in_sizes; (void)n_in; (void)out_size; (void)ws_size;
  const int* x = (const int*)d_in[0];
  const int* mask = (const int*)d_in[1];
  const int* clss = (const int*)d_in[2];
  const float* emb = (const float*)d_in[3];
  const float* pos = (const float*)d_in[4];
  const float* wq = (const float*)d_in[5];
  const float* wk = (const float*)d_in[6];
  const float* wv = (const float*)d_in[7];
  const float* wo = (const float*)d_in[8];
  const float* wqg = (const float*)d_in[9];
  const float* wkg = (const float*)d_in[10];
  const float* wvg = (const float*)d_in[11];
  float* out = (float*)d_out;

  char* ws = (char*)d_ws;
  size_t off = 0;
  auto alloc = [&](size_t n) { char* p = ws + off; off = (off + n + 255) & ~(size_t)255; return p; };
  const size_t SZ = (size_t)2 * 12 * 4096 * 64 * 2;  // one (B,H,S,DH) bf16 buffer
  u16* hb = (u16*)alloc(SZ);
  u16* wt = (u16*)alloc((size_t)7 * 768 * 768 * 2);
  u16* qb = (u16*)alloc(SZ);
  u16* kb = (u16*)alloc(SZ);
  u16* vb = (u16*)alloc(SZ);
  u16* kgb = (u16*)alloc(SZ);
  u16* vgb = (u16*)alloc(SZ);
  u16* qgb = (u16*)alloc(SZ);
  u16* vts = (u16*)alloc(SZ);
  u16* vgts = (u16*)alloc(SZ);
  u16* kcls = (u16*)alloc((size_t)24 * 64 * 64 * 2);
  u16* vtcls = (u16*)alloc((size_t)24 * 64 * 64 * 2);
  u8* mcls = (u8*)alloc(256);
  u8* isg = (u8*)alloc(4096);
  u8* kval = (u8*)alloc(2 * 4096);
  u16* aout = (u16*)alloc(SZ);
  float* pm = (float*)alloc((size_t)192 * 64 * 4);
  float* pl = (float*)alloc((size_t)192 * 64 * 4);
  float* pacc = (float*)alloc((size_t)192 * 4096 * 4);

  WPtrs wp;
  wp.p[0] = wq; wp.p[1] = wk; wp.p[2] = wv; wp.p[3] = wkg; wp.p[4] = wvg; wp.p[5] = wqg; wp.p[6] = wo;

  wconv_kernel<<<dim3(144, 7), 256, 0, stream>>>(wp, wt);
  embed_kernel<<<2048, 256, 0, stream>>>(x, emb, pos, hb);
  isg_kernel<<<1, 256, 0, stream>>>(clss, mask, isg, kval);

  Outs6 o6;
  o6.p[0] = qb; o6.p[1] = kb; o6.p[2] = vb; o6.p[3] = kgb; o6.p[4] = vgb; o6.p[5] = qgb;
  gemm_kernel<0><<<dim3(36, 64), 256, 0, stream>>>(hb, wt, o6, nullptr);

  transp_kernel<<<dim3(1536, 2), 256, 0, stream>>>(vb, vts, vgb, vgts);
  gcls_kernel<<<24, 256, 0, stream>>>(kb, vb, clss, mask, kcls, vtcls, mcls);

  ogp_kernel<<<192, 64, 0, stream>>>(qgb, kgb, vgts, clss, mask, pm, pl, pacc);
  band_kernel<<<768, 256, 0, stream>>>(qb, kb, vts, kcls, vtcls, mcls, kval, aout);
  ogm_kernel<<<24, 256, 0, stream>>>(pm, pl, pacc, clss, aout);

  Outs6 dummy = {};
  gemm_kernel<1><<<dim3(6, 64), 256, 0, stream>>>(aout, wt + (size_t)6 * 768 * 768, dummy, out);
}

// Round 4
// 348.333 us; speedup vs baseline: 1.1303x; 1.1303x over previous
//
#include <hip/hip_runtime.h>
#include <stdint.h>

typedef unsigned short u16;
typedef unsigned char u8;
typedef __attribute__((ext_vector_type(8))) short short8x;
typedef __attribute__((ext_vector_type(4))) float f32x4;

#define DEV static __device__ __forceinline__

DEV u16 f2bf(float f) {
  union { float f; unsigned u; } v; v.f = f;
  unsigned r = v.u + 0x7FFFu + ((v.u >> 16) & 1u);
  return (u16)(r >> 16);
}
DEV int imin(int a, int b) { return a < b ? a : b; }
DEV int imax(int a, int b) { return a > b ? a : b; }

DEV float ex2(float x) { return __builtin_exp2f(x); }

DEV void gload16(const void* g, void* l) {
  __builtin_amdgcn_global_load_lds((const __attribute__((address_space(1))) void*)g,
                                   (__attribute__((address_space(3))) void*)l, 16, 0, 0);
}

#define LOG2E 1.44269504f

// ---------------------------------------------------------------------------
// Weight convert+transpose: w[k][n] fp32 -> wt[mat][n][k] bf16 (7 mats)
struct WPtrs { const float* p[7]; };

__global__ __launch_bounds__(256) void wconv_kernel(WPtrs wp, u16* __restrict__ wt) {
  const int mat = blockIdx.y;
  const int kt = blockIdx.x % 12, nt = blockIdx.x / 12;
  const float* __restrict__ w = wp.p[mat];
  __shared__ float tile[64][72];
  const int t = threadIdx.x;
  {
    const int kk = t >> 2, n0 = (t & 3) * 16;
    const float* src = w + (size_t)(kt * 64 + kk) * 768 + nt * 64 + n0;
#pragma unroll
    for (int i = 0; i < 4; ++i)
      *(float4*)&tile[kk][n0 + i * 4] = *(const float4*)(src + i * 4);
  }
  __syncthreads();
  {
    const int nn = t >> 2, k0 = (t & 3) * 16;
    u16* dst = wt + (size_t)(mat * 768 + nt * 64 + nn) * 768 + kt * 64 + k0;
    short8x v0, v1;
#pragma unroll
    for (int j = 0; j < 8; ++j) {
      v0[j] = (short)f2bf(tile[k0 + j][nn]);
      v1[j] = (short)f2bf(tile[k0 + 8 + j][nn]);
    }
    *(short8x*)dst = v0;
    *(short8x*)(dst + 8) = v1;
  }
}

// ---------------------------------------------------------------------------
// h = emb[x] + pos  -> bf16  (8192 x 768)
__global__ __launch_bounds__(256) void embed_kernel(const int* __restrict__ x, const float* __restrict__ emb,
                                                    const float* __restrict__ pos, u16* __restrict__ hb) {
  const int n4 = 2 * 4096 * 192;
  for (int i = blockIdx.x * 256 + threadIdx.x; i < n4; i += gridDim.x * 256) {
    const int r = i / 192;
    const int d4 = i - r * 192;
    const int s = r & 4095;
    const int tok = x[r];
    const float4 e = *(const float4*)(emb + (size_t)tok * 768 + d4 * 4);
    const float4 p = *(const float4*)(pos + (size_t)s * 768 + d4 * 4);
    union { u16 u[4]; uint2 v; } o;
    o.u[0] = f2bf(e.x + p.x);
    o.u[1] = f2bf(e.y + p.y);
    o.u[2] = f2bf(e.z + p.z);
    o.u[3] = f2bf(e.w + p.w);
    *(uint2*)(hb + (size_t)r * 768 + d4 * 4) = o.v;
  }
}

// ---------------------------------------------------------------------------
// isg flags; kval[b][key] = mask && !isg (band keys); mval[b][key] = mask != 0
__global__ __launch_bounds__(256) void isg_kernel(const int* __restrict__ clss, const int* __restrict__ mask,
                                                  u8* __restrict__ isg, u8* __restrict__ kval,
                                                  u8* __restrict__ mval) {
  const int t = threadIdx.x;
  for (int i = t; i < 4096; i += 256) isg[i] = 0;
  __syncthreads();
  if (t < 64) isg[clss[t]] = 1;
  __syncthreads();
  for (int b = 0; b < 2; ++b)
    for (int i = t; i < 4096; i += 256) {
      const u8 m = (u8)(mask[b * 4096 + i] != 0);
      mval[b * 4096 + i] = m;
      kval[b * 4096 + i] = (u8)(m & (isg[i] == 0));
    }
}

// ---------------------------------------------------------------------------
// h[clss] gather -> hg[128][768] bf16 (rows: b*64+g)
__global__ __launch_bounds__(256) void hgather_kernel(const u16* __restrict__ hb, const int* __restrict__ clss,
                                                      u16* __restrict__ hg) {
  const int i = blockIdx.x * 256 + threadIdx.x;   // 12288 vec8 elems
  const int r = i / 96, c8 = i - r * 96;
  const int b = r >> 6, g = r & 63;
  const int s = clss[g];
  *(short8x*)(hg + (size_t)r * 768 + c8 * 8) =
      *(const short8x*)(hb + ((size_t)b * 4096 + s) * 768 + c8 * 8);
}

// ---------------------------------------------------------------------------
// 128x128x32 bf16 MFMA GEMM, B pre-transposed (N x K), global_load_lds staging.
// MODE 0: A=h (8192x768), Bt=Wt mats 0..4: write q,k,v,kg,vg in (B,H,S,DH) bf16
//         (q scaled by DH^-0.5 * log2e)
// MODE 1: A=attn_out bf16 (8192x768), Bt=woT: write fp32 d_out row-major
// MODE 2: A=hg (128x768), Bt=wqgT: write qgc compact (B,H,64,DH) bf16, scaled
struct Outs6 { u16* p[6]; };

template <int MODE>
__global__ __launch_bounds__(256) void gemm_kernel(const u16* __restrict__ A, const u16* __restrict__ Bt,
                                                   Outs6 outs, float* __restrict__ outF) {
  __shared__ __align__(16) u16 smA[128 * 32];
  __shared__ __align__(16) u16 smB[128 * 32];
  const int t = threadIdx.x;
  const int l = t & 63, w = t >> 6;
  const int l15 = l & 15, grp = l >> 4;
  const int wm = w >> 1, wn = w & 1;
  const int m0 = blockIdx.y * 128, n0 = blockIdx.x * 128;
  const f32x4 zero4 = {0.f, 0.f, 0.f, 0.f};
  f32x4 acc[4][4];
#pragma unroll
  for (int mi = 0; mi < 4; ++mi)
#pragma unroll
    for (int ni = 0; ni < 4; ++ni) acc[mi][ni] = zero4;

  const int srow = w * 32 + (l >> 2);
  const int scol = (l & 3) * 8;
  const u16* gA = A + (size_t)(m0 + srow) * 768 + scol;
  const u16* gB = Bt + (size_t)(n0 + srow) * 768 + scol;
  u16* lA = smA + w * 1024;
  u16* lB = smB + w * 1024;

  for (int kb = 0; kb < 24; ++kb) {
    __syncthreads();
    const size_t ko = (size_t)kb * 32;
    gload16(gA + ko, lA);
    gload16(gA + 16 * 768 + ko, lA + 512);
    gload16(gB + ko, lB);
    gload16(gB + 16 * 768 + ko, lB + 512);
    __syncthreads();
    short8x af[4], bfr[4];
#pragma unroll
    for (int mi = 0; mi < 4; ++mi)
      af[mi] = *(const short8x*)(smA + (wm * 64 + mi * 16 + l15) * 32 + grp * 8);
#pragma unroll
    for (int ni = 0; ni < 4; ++ni)
      bfr[ni] = *(const short8x*)(smB + (wn * 64 + ni * 16 + l15) * 32 + grp * 8);
#pragma unroll
    for (int mi = 0; mi < 4; ++mi)
#pragma unroll
      for (int ni = 0; ni < 4; ++ni)
        acc[mi][ni] = __builtin_amdgcn_mfma_f32_16x16x32_bf16(af[mi], bfr[ni], acc[mi][ni], 0, 0, 0);
  }

  if (MODE == 0) {
    const int mat = blockIdx.x / 6;               // 5 mats: q,k,v,kg,vg
    const int inn0 = n0 - mat * 768 + wn * 64;
    const float scl = (mat == 0) ? 0.125f * LOG2E : 1.0f;
    u16* __restrict__ base = outs.p[mat];
#pragma unroll
    for (int mi = 0; mi < 4; ++mi)
#pragma unroll
      for (int ni = 0; ni < 4; ++ni) {
        const int col = inn0 + ni * 16 + l15;
        const int hd = col >> 6, dh = col & 63;
#pragma unroll
        for (int rr = 0; rr < 4; ++rr) {
          const int row = m0 + wm * 64 + mi * 16 + grp * 4 + rr;
          const int b = row >> 12, s = row & 4095;
          base[((size_t)(b * 12 + hd) * 4096 + s) * 64 + dh] = f2bf(acc[mi][ni][rr] * scl);
        }
      }
  } else if (MODE == 1) {
#pragma unroll
    for (int mi = 0; mi < 4; ++mi)
#pragma unroll
      for (int rr = 0; rr < 4; ++rr) {
        const int row = m0 + wm * 64 + mi * 16 + grp * 4 + rr;
#pragma unroll
        for (int ni = 0; ni < 4; ++ni) {
          const int col = n0 + wn * 64 + ni * 16 + l15;
          outF[(size_t)row * 768 + col] = acc[mi][ni][rr];
        }
      }
  } else {  // MODE 2: qg compact
    u16* __restrict__ base = outs.p[0];
#pragma unroll
    for (int mi = 0; mi < 4; ++mi)
#pragma unroll
      for (int ni = 0; ni < 4; ++ni) {
        const int col = n0 + wn * 64 + ni * 16 + l15;
        const int hd = col >> 6, dh = col & 63;
#pragma unroll
        for (int rr = 0; rr < 4; ++rr) {
          const int row = wm * 64 + mi * 16 + grp * 4 + rr;   // 0..127
          const int b = row >> 6, g = row & 63;
          base[((size_t)(b * 12 + hd) * 64 + g) * 64 + dh] = f2bf(acc[mi][ni][rr] * 0.125f * LOG2E);
        }
      }
  }
}

// ---------------------------------------------------------------------------
// (B,H,S,DH) -> (B,H,DH,S) bf16, two buffers (v->vT, vg->vgT)
__global__ __launch_bounds__(256) void transp_kernel(const u16* __restrict__ in0, u16* __restrict__ out0,
                                                     const u16* __restrict__ in1, u16* __restrict__ out1) {
  const u16* src = blockIdx.y ? in1 : in0;
  u16* dst = blockIdx.y ? out1 : out0;
  const int bh = blockIdx.x >> 6;
  const int s0 = (blockIdx.x & 63) << 6;
  __shared__ u16 tile[64][80];
  const int t = threadIdx.x;
  {
    const int sl = t >> 2, d0 = (t & 3) * 16;
    const u16* p = src + ((size_t)bh * 4096 + s0 + sl) * 64 + d0;
    *(short8x*)&tile[sl][d0] = *(const short8x*)p;
    *(short8x*)&tile[sl][d0 + 8] = *(const short8x*)(p + 8);
  }
  __syncthreads();
  {
    const int dh = t >> 2, q0 = (t & 3) * 16;
    short8x v0, v1;
#pragma unroll
    for (int j = 0; j < 8; ++j) {
      v0[j] = (short)tile[q0 + j][dh];
      v1[j] = (short)tile[q0 + 8 + j][dh];
    }
    u16* o = dst + ((size_t)bh * 64 + dh) * 4096 + s0 + q0;
    *(short8x*)o = v0;
    *(short8x*)(o + 8) = v1;
  }
}

// ---------------------------------------------------------------------------
// Gather K rows at clss -> kcls; v rows at clss transposed -> vtcls; mask at clss.
__global__ __launch_bounds__(256) void gcls_kernel(const u16* __restrict__ kB, const u16* __restrict__ vB,
                                                   const int* __restrict__ clss, const int* __restrict__ mask,
                                                   u16* __restrict__ kcls, u16* __restrict__ vtcls,
                                                   u8* __restrict__ mcls) {
  const int bh = blockIdx.x;
  const int b = bh / 12;
  __shared__ u16 tile[64][80];
  const int t = threadIdx.x;
  {
    const int g = t >> 2, d0 = (t & 3) * 16;
    const int row = clss[g];
    const u16* pk = kB + ((size_t)bh * 4096 + row) * 64 + d0;
    u16* ok = kcls + ((size_t)bh * 64 + g) * 64 + d0;
    *(short8x*)ok = *(const short8x*)pk;
    *(short8x*)(ok + 8) = *(const short8x*)(pk + 8);
    const u16* pv = vB + ((size_t)bh * 4096 + row) * 64 + d0;
    *(short8x*)&tile[g][d0] = *(const short8x*)pv;
    *(short8x*)&tile[g][d0 + 8] = *(const short8x*)(pv + 8);
  }
  if (t < 64) mcls[b * 64 + t] = (mask[(size_t)b * 4096 + clss[t]] != 0) ? 1 : 0;
  __syncthreads();
  {
    const int dh = t >> 2, g0 = (t & 3) * 16;
    short8x v0, v1;
#pragma unroll
    for (int j = 0; j < 8; ++j) {
      v0[j] = (short)tile[g0 + j][dh];
      v1[j] = (short)tile[g0 + 8 + j][dh];
    }
    u16* o = vtcls + ((size_t)bh * 64 + dh) * 64 + g0;
    *(short8x*)o = v0;
    *(short8x*)(o + 8) = v1;
  }
}

// ---------------------------------------------------------------------------
// Fused band attention (blocks 192..1727; 16 q/wave, per-wave flash loop) +
// global-token attention partials (blocks 0..191; 16 q/wave, 1/8 key slice).
struct FusedArgs {
  const u16 *qB, *kB, *vT, *kcls, *vtcls, *qgc, *kgB, *vgT;
  const u8 *mcls, *kval, *mval;
  u16* aout;
  float *pm, *pl, *pacc;
};

__global__ __launch_bounds__(256, 4) void band_kernel(FusedArgs a) {
  const int t = threadIdx.x;
  const int w = t >> 6, l = t & 63, l15 = l & 15, grp = l >> 4;
  __shared__ u16 Pt[4][1024];  // per-wave 16x64 bf16 P, XOR-swizzled
  u16* P = Pt[w];
  const f32x4 zero4 = {0.f, 0.f, 0.f, 0.f};

  if (blockIdx.x < 192) {
    // ---- global-token attention partial (bh, slice) ----
    const int blk = blockIdx.x;
    const int bh = blk >> 3, sl = blk & 7;
    const int b = bh / 12;
    const u16* kgb = a.kgB + (size_t)bh * 4096 * 64;
    const u16* vgb = a.vgT + (size_t)bh * 64 * 4096;

    short8x qf[2];
#pragma unroll
    for (int ks = 0; ks < 2; ++ks)
      qf[ks] = *(const short8x*)(a.qgc + ((size_t)bh * 64 + w * 16 + l15) * 64 + ks * 32 + grp * 8);

    f32x4 accD[4];
    float mst[4], lst[4];
#pragma unroll
    for (int j = 0; j < 4; ++j) { accD[j] = zero4; mst[j] = -60.f; lst[j] = 0.f; }

    for (int tt = sl * 8; tt < sl * 8 + 8; ++tt) {
      const int kbase = tt * 64;
      int kok[4];
      f32x4 sf[4];
#pragma unroll
      for (int kj = 0; kj < 4; ++kj) {
        kok[kj] = a.mval[b * 4096 + kbase + kj * 16 + l15];
        sf[kj] = zero4;
      }
#pragma unroll
      for (int ks = 0; ks < 2; ++ks) {
        short8x kfk[4];
#pragma unroll
        for (int kj = 0; kj < 4; ++kj)
          kfk[kj] = *(const short8x*)(kgb + (size_t)(kbase + kj * 16 + l15) * 64 + ks * 32 + grp * 8);
#pragma unroll
        for (int kj = 0; kj < 4; ++kj)
          sf[kj] = __builtin_amdgcn_mfma_f32_16x16x32_bf16(qf[ks], kfk[kj], sf[kj], 0, 0, 0);
      }
      const int allok = kok[0] & kok[1] & kok[2] & kok[3];
      float tm[4];
#pragma unroll
      for (int rr = 0; rr < 4; ++rr) tm[rr] = -1e30f;
      if (__all(allok != 0)) {
#pragma unroll
        for (int kj = 0; kj < 4; ++kj)
#pragma unroll
          for (int rr = 0; rr < 4; ++rr) tm[rr] = fmaxf(tm[rr], sf[kj][rr]);
      } else {
#pragma unroll
        for (int kj = 0; kj < 4; ++kj)
#pragma unroll
          for (int rr = 0; rr < 4; ++rr) {
            const float sv = kok[kj] ? sf[kj][rr] : -1e30f;
            sf[kj][rr] = sv;
            tm[rr] = fmaxf(tm[rr], sv);
          }
      }
#pragma unroll
      for (int rr = 0; rr < 4; ++rr) {
        float v = tm[rr];
        v = fmaxf(v, __shfl_xor(v, 1));
        v = fmaxf(v, __shfl_xor(v, 2));
        v = fmaxf(v, __shfl_xor(v, 4));
        v = fmaxf(v, __shfl_xor(v, 8));
        const float mo = mst[rr];
        const float mn = fmaxf(mo, v);
        const float sc = ex2(mo - mn);
        float ps = 0.f;
#pragma unroll
        for (int kj = 0; kj < 4; ++kj) {
          const float p = ex2(sf[kj][rr] - mn);
          sf[kj][rr] = p;
          ps += p;
        }
        ps += __shfl_xor(ps, 1);
        ps += __shfl_xor(ps, 2);
        ps += __shfl_xor(ps, 4);
        ps += __shfl_xor(ps, 8);
        lst[rr] = lst[rr] * sc + ps;
        mst[rr] = mn;
#pragma unroll
        for (int dj = 0; dj < 4; ++dj) accD[dj][rr] *= sc;
      }
#pragma unroll
      for (int rr = 0; rr < 4; ++rr) {
        const int ql = grp * 4 + rr;
        const int swz = (ql & 7) << 4;
        char* rowp = (char*)P + ql * 128;
#pragma unroll
        for (int kj = 0; kj < 4; ++kj) {
          const int byo = ((kj * 16 + l15) * 2) ^ swz;
          *(u16*)(rowp + byo) = f2bf(sf[kj][rr]);
        }
      }
      asm volatile("s_waitcnt lgkmcnt(0)" ::: "memory");
      __builtin_amdgcn_sched_barrier(0);
#pragma unroll
      for (int ks = 0; ks < 2; ++ks) {
        const int byo = (l15 * 128 + ks * 64 + grp * 16) ^ ((l15 & 7) << 4);
        const short8x pak = *(const short8x*)((const char*)P + byo);
        short8x vfk[4];
#pragma unroll
        for (int dj = 0; dj < 4; ++dj) {
          const int dh = dj * 16 + l15;
          vfk[dj] = *(const short8x*)(vgb + (size_t)dh * 4096 + kbase + ks * 32 + grp * 8);
        }
#pragma unroll
        for (int dj = 0; dj < 4; ++dj)
          accD[dj] = __builtin_amdgcn_mfma_f32_16x16x32_bf16(pak, vfk[dj], accD[dj], 0, 0, 0);
      }
      asm volatile("s_waitcnt lgkmcnt(0)" ::: "memory");
      __builtin_amdgcn_sched_barrier(0);
    }

    const int pbase = (bh * 8 + sl) * 64;
#pragma unroll
    for (int dj = 0; dj < 4; ++dj)
#pragma unroll
      for (int rr = 0; rr < 4; ++rr) {
        const int row = w * 16 + grp * 4 + rr;
        a.pacc[((size_t)pbase + row) * 64 + dj * 16 + l15] = accD[dj][rr];
      }
    if (l15 == 0)
#pragma unroll
      for (int rr = 0; rr < 4; ++rr) {
        const int row = w * 16 + grp * 4 + rr;
        a.pm[pbase + row] = mst[rr];
        a.pl[pbase + row] = lst[rr];
      }
    return;
  }

  // ---- band path ----
  int bid = blockIdx.x - 192;
  bid = (bid & 7) * 192 + (bid >> 3);   // XCD chunking (1536 = 8 * 192, bijective)
  const int qblk = bid & 63;
  const int h = (bid >> 6) % 12;
  const int b = bid / 768;
  const int bh = b * 12 + h;
  const int q0 = qblk * 64 + w * 16;

  const u16* kbh = a.kB + (size_t)bh * 4096 * 64;
  const u16* vbh = a.vT + (size_t)bh * 64 * 4096;
  const u16* kcb = a.kcls + (size_t)bh * 4096;
  const u16* vcb = a.vtcls + (size_t)bh * 4096;
  const u8* kvb = a.kval + b * 4096;

  short8x qf[2];
#pragma unroll
  for (int ks = 0; ks < 2; ++ks)
    qf[ks] = *(const short8x*)(a.qB + ((size_t)bh * 4096 + q0 + l15) * 64 + ks * 32 + grp * 8);

  f32x4 accD[4];
  float mst[4], lst[4];
#pragma unroll
  for (int j = 0; j < 4; ++j) { accD[j] = zero4; mst[j] = -60.f; lst[j] = 0.f; }

  const int tlo = imax(0, (q0 - 256) >> 6);
  const int thi = imin(63, (q0 + 271) >> 6);

  for (int tt = tlo; tt <= thi + 1; ++tt) {
    const bool isG = (tt == thi + 1);
    const int kbase = isG ? 0 : tt * 64;
    const u16* kr = isG ? kcb : (kbh + (size_t)kbase * 64);

    int kok[4];
#pragma unroll
    for (int kj = 0; kj < 4; ++kj) {
      const int key16 = kj * 16 + l15;
      kok[kj] = isG ? a.mcls[b * 64 + key16] : kvb[kbase + key16];
    }

    f32x4 sf[4];
#pragma unroll
    for (int kj = 0; kj < 4; ++kj) sf[kj] = zero4;
#pragma unroll
    for (int ks = 0; ks < 2; ++ks) {
      short8x kfk[4];
#pragma unroll
      for (int kj = 0; kj < 4; ++kj)
        kfk[kj] = *(const short8x*)(kr + (size_t)(kj * 16 + l15) * 64 + ks * 32 + grp * 8);
#pragma unroll
      for (int kj = 0; kj < 4; ++kj)
        sf[kj] = __builtin_amdgcn_mfma_f32_16x16x32_bf16(qf[ks], kfk[kj], sf[kj], 0, 0, 0);
    }

    // masking: interior fast path skips all per-element work
    const int allok = kok[0] & kok[1] & kok[2] & kok[3];
    const bool fast = !isG && (kbase >= q0 - 241) && (kbase <= q0 + 193) && __all(allok != 0);
    float tm[4];
#pragma unroll
    for (int rr = 0; rr < 4; ++rr) tm[rr] = -1e30f;
    if (fast) {
#pragma unroll
      for (int kj = 0; kj < 4; ++kj)
#pragma unroll
        for (int rr = 0; rr < 4; ++rr) tm[rr] = fmaxf(tm[rr], sf[kj][rr]);
    } else {
      const int qr0 = q0 + grp * 4;
#pragma unroll
      for (int kj = 0; kj < 4; ++kj)
#pragma unroll
        for (int rr = 0; rr < 4; ++rr) {
          int valid = kok[kj];
          if (!isG) {
            const int rel = kbase + kj * 16 + l15 - (qr0 + rr);
            valid = valid & (int)(rel >= -256) & (int)(rel <= 256);
          }
          const float sv = valid ? sf[kj][rr] : -1e30f;
          sf[kj][rr] = sv;
          tm[rr] = fmaxf(tm[rr], sv);
        }
    }
    float tmr[4];
#pragma unroll
    for (int rr = 0; rr < 4; ++rr) {
      float v = tm[rr];
      v = fmaxf(v, __shfl_xor(v, 1));
      v = fmaxf(v, __shfl_xor(v, 2));
      v = fmaxf(v, __shfl_xor(v, 4));
      v = fmaxf(v, __shfl_xor(v, 8));
      tmr[rr] = v;
    }

    // defer-max: skip rescale when growth <= 8 (log2 units), wave-uniform
    int lok = 1;
#pragma unroll
    for (int rr = 0; rr < 4; ++rr) lok &= (int)(tmr[rr] <= mst[rr] + 8.f);
    if (__all(lok)) {
#pragma unroll
      for (int rr = 0; rr < 4; ++rr) {
        const float mo = mst[rr];
        float ps = 0.f;
#pragma unroll
        for (int kj = 0; kj < 4; ++kj) {
          const float p = ex2(sf[kj][rr] - mo);
          sf[kj][rr] = p;
          ps += p;
        }
        ps += __shfl_xor(ps, 1);
        ps += __shfl_xor(ps, 2);
        ps += __shfl_xor(ps, 4);
        ps += __shfl_xor(ps, 8);
        lst[rr] += ps;
      }
    } else {
#pragma unroll
      for (int rr = 0; rr < 4; ++rr) {
        const float mo = mst[rr];
        const float mn = fmaxf(mo, tmr[rr]);
        const float sc = ex2(mo - mn);
        float ps = 0.f;
#pragma unroll
        for (int kj = 0; kj < 4; ++kj) {
          const float p = ex2(sf[kj][rr] - mn);
          sf[kj][rr] = p;
          ps += p;
        }
        ps += __shfl_xor(ps, 1);
        ps += __shfl_xor(ps, 2);
        ps += __shfl_xor(ps, 4);
        ps += __shfl_xor(ps, 8);
        lst[rr] = lst[rr] * sc + ps;
        mst[rr] = mn;
#pragma unroll
        for (int dj = 0; dj < 4; ++dj) accD[dj][rr] *= sc;
      }
    }

    // P -> LDS bf16 (row*128B + key*2B, XOR swizzle bits 4-6 by row&7)
#pragma unroll
    for (int rr = 0; rr < 4; ++rr) {
      const int ql = grp * 4 + rr;
      const int swz = (ql & 7) << 4;
      char* rowp = (char*)P + ql * 128;
#pragma unroll
      for (int kj = 0; kj < 4; ++kj) {
        const int byo = ((kj * 16 + l15) * 2) ^ swz;
        *(u16*)(rowp + byo) = f2bf(sf[kj][rr]);
      }
    }
    asm volatile("s_waitcnt lgkmcnt(0)" ::: "memory");
    __builtin_amdgcn_sched_barrier(0);

    // PV: A = P (LDS), B = V^T (global, K-contiguous)
#pragma unroll
    for (int ks = 0; ks < 2; ++ks) {
      const int byo = (l15 * 128 + ks * 64 + grp * 16) ^ ((l15 & 7) << 4);
      const short8x pak = *(const short8x*)((const char*)P + byo);
      short8x vfk[4];
#pragma unroll
      for (int dj = 0; dj < 4; ++dj) {
        const int dh = dj * 16 + l15;
        const u16* vr = isG ? (vcb + dh * 64) : (vbh + (size_t)dh * 4096 + kbase);
        vfk[dj] = *(const short8x*)(vr + ks * 32 + grp * 8);
      }
#pragma unroll
      for (int dj = 0; dj < 4; ++dj)
        accD[dj] = __builtin_amdgcn_mfma_f32_16x16x32_bf16(pak, vfk[dj], accD[dj], 0, 0, 0);
    }
    asm volatile("s_waitcnt lgkmcnt(0)" ::: "memory");
    __builtin_amdgcn_sched_barrier(0);
  }

  // finalize: divide by row sums, store (B,S,D) bf16
  u16* ob = a.aout + ((size_t)b * 4096 + q0) * 768 + h * 64;
#pragma unroll
  for (int rr = 0; rr < 4; ++rr) {
    const float inv = 1.f / lst[rr];
    const int row = grp * 4 + rr;
#pragma unroll
    for (int dj = 0; dj < 4; ++dj)
      ob[(size_t)row * 768 + dj * 16 + l15] = f2bf(accD[dj][rr] * inv);
  }
}

// ---------------------------------------------------------------------------
// Global-token attention merge: combine 8 key-slice partials, overwrite clss rows of aout.
__global__ __launch_bounds__(256) void ogm_kernel(const float* __restrict__ pm, const float* __restrict__ pl,
                                                  const float* __restrict__ pacc, const int* __restrict__ clss,
                                                  u16* __restrict__ aout) {
  const int bh = blockIdx.x;
  const int b = bh / 12, h = bh % 12;
  const int t = threadIdx.x;
  const int r = t >> 2, cs = (t & 3) * 16;
  float mv[8];
  float M = -1e30f;
#pragma unroll
  for (int s = 0; s < 8; ++s) {
    mv[s] = pm[(bh * 8 + s) * 64 + r];
    M = fmaxf(M, mv[s]);
  }
  float L = 0.f, f[8];
#pragma unroll
  for (int s = 0; s < 8; ++s) {
    f[s] = ex2(mv[s] - M);
    L += pl[(bh * 8 + s) * 64 + r] * f[s];
  }
  float o[16];
#pragma unroll
  for (int j = 0; j < 16; ++j) o[j] = 0.f;
#pragma unroll
  for (int s = 0; s < 8; ++s) {
    const float* pr = pacc + (size_t)(bh * 8 + s) * 4096 + r * 64 + cs;
#pragma unroll
    for (int j4 = 0; j4 < 4; ++j4) {
      const float4 a = *(const float4*)(pr + j4 * 4);
      o[j4 * 4 + 0] += a.x * f[s];
      o[j4 * 4 + 1] += a.y * f[s];
      o[j4 * 4 + 2] += a.z * f[s];
      o[j4 * 4 + 3] += a.w * f[s];
    }
  }
  const float inv = 1.f / L;
  short8x v0, v1;
#pragma unroll
  for (int j = 0; j < 8; ++j) {
    v0[j] = (short)f2bf(o[j] * inv);
    v1[j] = (short)f2bf(o[8 + j] * inv);
  }
  u16* op = aout + ((size_t)b * 4096 + clss[r]) * 768 + h * 64 + cs;
  *(short8x*)op = v0;
  *(short8x*)(op + 8) = v1;
}

// ---------------------------------------------------------------------------
extern "C" void kernel_launch(void* const* d_in, const int* in_sizes, int n_in,
                              void* d_out, int out_size, void* d_ws, size_t ws_size,
                              hipStream_t stream) {
  (void)in_sizes; (void)n_in; (void)out_size; (void)ws_size;
  const int* x = (const int*)d_in[0];
  const int* mask = (const int*)d_in[1];
  const int* clss = (const int*)d_in[2];
  const float* emb = (const float*)d_in[3];
  const float* pos = (const float*)d_in[4];
  const float* wq = (const float*)d_in[5];
  const float* wk = (const float*)d_in[6];
  const float* wv = (const float*)d_in[7];
  const float* wo = (const float*)d_in[8];
  const float* wqg = (const float*)d_in[9];
  const float* wkg = (const float*)d_in[10];
  const float* wvg = (const float*)d_in[11];
  float* out = (float*)d_out;

  char* ws = (char*)d_ws;
  size_t off = 0;
  auto alloc = [&](size_t n) { char* p = ws + off; off = (off + n + 255) & ~(size_t)255; return p; };
  const size_t SZ = (size_t)2 * 12 * 4096 * 64 * 2;  // one (B,H,S,DH) bf16 buffer
  u16* hb = (u16*)alloc(SZ);
  u16* wt = (u16*)alloc((size_t)7 * 768 * 768 * 2);
  u16* qb = (u16*)alloc(SZ);
  u16* kb = (u16*)alloc(SZ);
  u16* vb = (u16*)alloc(SZ);
  u16* kgb = (u16*)alloc(SZ);
  u16* vgb = (u16*)alloc(SZ);
  u16* vts = (u16*)alloc(SZ);
  u16* vgts = (u16*)alloc(SZ);
  u16* hg = (u16*)alloc((size_t)128 * 768 * 2);
  u16* qgc = (u16*)alloc((size_t)24 * 64 * 64 * 2);
  u16* kcls = (u16*)alloc((size_t)24 * 64 * 64 * 2);
  u16* vtcls = (u16*)alloc((size_t)24 * 64 * 64 * 2);
  u8* mcls = (u8*)alloc(256);
  u8* isg = (u8*)alloc(4096);
  u8* kval = (u8*)alloc(2 * 4096);
  u8* mval = (u8*)alloc(2 * 4096);
  u16* aout = (u16*)alloc(SZ);
  float* pm = (float*)alloc((size_t)192 * 64 * 4);
  float* pl = (float*)alloc((size_t)192 * 64 * 4);
  float* pacc = (float*)alloc((size_t)192 * 4096 * 4);

  WPtrs wp;
  wp.p[0] = wq; wp.p[1] = wk; wp.p[2] = wv; wp.p[3] = wkg; wp.p[4] = wvg; wp.p[5] = wqg; wp.p[6] = wo;

  wconv_kernel<<<dim3(144, 7), 256, 0, stream>>>(wp, wt);
  embed_kernel<<<2048, 256, 0, stream>>>(x, emb, pos, hb);
  isg_kernel<<<1, 256, 0, stream>>>(clss, mask, isg, kval, mval);

  Outs6 o5;
  o5.p[0] = qb; o5.p[1] = kb; o5.p[2] = vb; o5.p[3] = kgb; o5.p[4] = vgb; o5.p[5] = nullptr;
  gemm_kernel<0><<<dim3(30, 64), 256, 0, stream>>>(hb, wt, o5, nullptr);

  hgather_kernel<<<48, 256, 0, stream>>>(hb, clss, hg);
  Outs6 oq = {};
  oq.p[0] = qgc;
  gemm_kernel<2><<<dim3(6, 1), 256, 0, stream>>>(hg, wt + (size_t)5 * 768 * 768, oq, nullptr);

  transp_kernel<<<dim3(1536, 2), 256, 0, stream>>>(vb, vts, vgb, vgts);
  gcls_kernel<<<24, 256, 0, stream>>>(kb, vb, clss, mask, kcls, vtcls, mcls);

  FusedArgs fa;
  fa.qB = qb; fa.kB = kb; fa.vT = vts; fa.kcls = kcls; fa.vtcls = vtcls;
  fa.qgc = qgc; fa.kgB = kgb; fa.vgT = vgts;
  fa.mcls = mcls; fa.kval = kval; fa.mval = mval;
  fa.aout = aout; fa.pm = pm; fa.pl = pl; fa.pacc = pacc;
  band_kernel<<<1728, 256, 0, stream>>>(fa);

  ogm_kernel<<<24, 256, 0, stream>>>(pm, pl, pacc, clss, aout);

  Outs6 dummy = {};
  gemm_kernel<1><<<dim3(6, 64), 256, 0, stream>>>(aout, wt + (size_t)6 * 768 * 768, dummy, out);
}

// Round 5
// 232.582 us; speedup vs baseline: 1.6928x; 1.4977x over previous
//
#include <hip/hip_runtime.h>
#include <stdint.h>

typedef unsigned short u16;
typedef unsigned char u8;
typedef unsigned int u32;
typedef __attribute__((ext_vector_type(8))) short short8x;
typedef __attribute__((ext_vector_type(4))) float f32x4;
typedef __attribute__((ext_vector_type(16))) float f32x16;

#define DEV static __device__ __forceinline__

DEV u16 f2bf(float f) {
  union { float f; unsigned u; } v; v.f = f;
  unsigned r = v.u + 0x7FFFu + ((v.u >> 16) & 1u);
  return (u16)(r >> 16);
}
DEV int imin(int a, int b) { return a < b ? a : b; }
DEV int imax(int a, int b) { return a > b ? a : b; }
DEV float ex2(float x) { return __builtin_exp2f(x); }

DEV void gload16(const void* g, void* l) {
  __builtin_amdgcn_global_load_lds((const __attribute__((address_space(1))) void*)g,
                                   (__attribute__((address_space(3))) void*)l, 16, 0, 0);
}

DEV u32 cvtpk_bf16(float lo, float hi) {
  u32 r;
  asm("v_cvt_pk_bf16_f32 %0, %1, %2" : "=v"(r) : "v"(lo), "v"(hi));
  return r;
}
DEV void plswap(u32& a, u32& b) {
  asm("v_permlane32_swap_b32 %0, %1" : "+v"(a), "+v"(b));
}

#define LOG2E 1.44269504f

// ---------------------------------------------------------------------------
// Weight convert+transpose: w[k][n] fp32 -> wt[mat][n][k] bf16 (7 mats)
struct WPtrs { const float* p[7]; };

__global__ __launch_bounds__(256) void wconv_kernel(WPtrs wp, u16* __restrict__ wt) {
  const int mat = blockIdx.y;
  const int kt = blockIdx.x % 12, nt = blockIdx.x / 12;
  const float* __restrict__ w = wp.p[mat];
  __shared__ float tile[64][72];
  const int t = threadIdx.x;
  {
    const int kk = t >> 2, n0 = (t & 3) * 16;
    const float* src = w + (size_t)(kt * 64 + kk) * 768 + nt * 64 + n0;
#pragma unroll
    for (int i = 0; i < 4; ++i)
      *(float4*)&tile[kk][n0 + i * 4] = *(const float4*)(src + i * 4);
  }
  __syncthreads();
  {
    const int nn = t >> 2, k0 = (t & 3) * 16;
    u16* dst = wt + (size_t)(mat * 768 + nt * 64 + nn) * 768 + kt * 64 + k0;
    short8x v0, v1;
#pragma unroll
    for (int j = 0; j < 8; ++j) {
      v0[j] = (short)f2bf(tile[k0 + j][nn]);
      v1[j] = (short)f2bf(tile[k0 + 8 + j][nn]);
    }
    *(short8x*)dst = v0;
    *(short8x*)(dst + 8) = v1;
  }
}

// ---------------------------------------------------------------------------
// h = emb[x] + pos  -> bf16  (8192 x 768)
__global__ __launch_bounds__(256) void embed_kernel(const int* __restrict__ x, const float* __restrict__ emb,
                                                    const float* __restrict__ pos, u16* __restrict__ hb) {
  const int n4 = 2 * 4096 * 192;
  for (int i = blockIdx.x * 256 + threadIdx.x; i < n4; i += gridDim.x * 256) {
    const int r = i / 192;
    const int d4 = i - r * 192;
    const int s = r & 4095;
    const int tok = x[r];
    const float4 e = *(const float4*)(emb + (size_t)tok * 768 + d4 * 4);
    const float4 p = *(const float4*)(pos + (size_t)s * 768 + d4 * 4);
    union { u16 u[4]; uint2 v; } o;
    o.u[0] = f2bf(e.x + p.x);
    o.u[1] = f2bf(e.y + p.y);
    o.u[2] = f2bf(e.z + p.z);
    o.u[3] = f2bf(e.w + p.w);
    *(uint2*)(hb + (size_t)r * 768 + d4 * 4) = o.v;
  }
}

// ---------------------------------------------------------------------------
// Validity bitmasks: kv32[b][i] bits = mask&&!isg for keys 32i..32i+31;
// mv32 = mask!=0 bits; mc32[b][0..1] = mask!=0 at clss[g] bits.
__global__ __launch_bounds__(256) void bits_kernel(const int* __restrict__ clss, const int* __restrict__ mask,
                                                   u32* __restrict__ kv32, u32* __restrict__ mv32,
                                                   u32* __restrict__ mc32) {
  __shared__ u8 isg[4096];
  const int t = threadIdx.x;
  for (int i = t; i < 4096; i += 256) isg[i] = 0;
  __syncthreads();
  if (t < 64) isg[clss[t]] = 1;
  __syncthreads();
  {
    const int b = t >> 7, i = t & 127;
    u32 kv = 0, mvv = 0;
    for (int j = 0; j < 32; ++j) {
      const int key = i * 32 + j;
      const u32 m = (u32)(mask[b * 4096 + key] != 0);
      mvv |= m << j;
      kv |= (m & (u32)(isg[key] == 0)) << j;
    }
    kv32[b * 128 + i] = kv;
    mv32[b * 128 + i] = mvv;
  }
  if (t < 4) {
    const int b = t >> 1, wi = t & 1;
    u32 mc = 0;
    for (int j = 0; j < 32; ++j) {
      const int g = wi * 32 + j;
      mc |= (u32)(mask[b * 4096 + clss[g]] != 0) << j;
    }
    mc32[b * 2 + wi] = mc;
  }
}

// ---------------------------------------------------------------------------
// h[clss] gather -> hg[128][768] bf16 (rows: b*64+g)
__global__ __launch_bounds__(256) void hgather_kernel(const u16* __restrict__ hb, const int* __restrict__ clss,
                                                      u16* __restrict__ hg) {
  const int i = blockIdx.x * 256 + threadIdx.x;
  const int r = i / 96, c8 = i - r * 96;
  const int b = r >> 6, g = r & 63;
  const int s = clss[g];
  *(short8x*)(hg + (size_t)r * 768 + c8 * 8) =
      *(const short8x*)(hb + ((size_t)b * 4096 + s) * 768 + c8 * 8);
}

// ---------------------------------------------------------------------------
// 128x128x32 bf16 MFMA GEMM, B pre-transposed (N x K), global_load_lds staging.
struct Outs6 { u16* p[6]; };

template <int MODE>
__global__ __launch_bounds__(256) void gemm_kernel(const u16* __restrict__ A, const u16* __restrict__ Bt,
                                                   Outs6 outs, float* __restrict__ outF) {
  __shared__ __align__(16) u16 smA[128 * 32];
  __shared__ __align__(16) u16 smB[128 * 32];
  const int t = threadIdx.x;
  const int l = t & 63, w = t >> 6;
  const int l15 = l & 15, grp = l >> 4;
  const int wm = w >> 1, wn = w & 1;
  const int m0 = blockIdx.y * 128, n0 = blockIdx.x * 128;
  const f32x4 zero4 = {0.f, 0.f, 0.f, 0.f};
  f32x4 acc[4][4];
#pragma unroll
  for (int mi = 0; mi < 4; ++mi)
#pragma unroll
    for (int ni = 0; ni < 4; ++ni) acc[mi][ni] = zero4;

  const int srow = w * 32 + (l >> 2);
  const int scol = (l & 3) * 8;
  const u16* gA = A + (size_t)(m0 + srow) * 768 + scol;
  const u16* gB = Bt + (size_t)(n0 + srow) * 768 + scol;
  u16* lA = smA + w * 1024;
  u16* lB = smB + w * 1024;

  for (int kb = 0; kb < 24; ++kb) {
    __syncthreads();
    const size_t ko = (size_t)kb * 32;
    gload16(gA + ko, lA);
    gload16(gA + 16 * 768 + ko, lA + 512);
    gload16(gB + ko, lB);
    gload16(gB + 16 * 768 + ko, lB + 512);
    __syncthreads();
    short8x af[4], bfr[4];
#pragma unroll
    for (int mi = 0; mi < 4; ++mi)
      af[mi] = *(const short8x*)(smA + (wm * 64 + mi * 16 + l15) * 32 + grp * 8);
#pragma unroll
    for (int ni = 0; ni < 4; ++ni)
      bfr[ni] = *(const short8x*)(smB + (wn * 64 + ni * 16 + l15) * 32 + grp * 8);
#pragma unroll
    for (int mi = 0; mi < 4; ++mi)
#pragma unroll
      for (int ni = 0; ni < 4; ++ni)
        acc[mi][ni] = __builtin_amdgcn_mfma_f32_16x16x32_bf16(af[mi], bfr[ni], acc[mi][ni], 0, 0, 0);
  }

  if (MODE == 0) {
    const int mat = blockIdx.x / 6;               // 5 mats: q,k,v,kg,vg
    const int inn0 = n0 - mat * 768 + wn * 64;
    const float scl = (mat == 0) ? 0.125f * LOG2E : 1.0f;
    u16* __restrict__ base = outs.p[mat];
#pragma unroll
    for (int mi = 0; mi < 4; ++mi)
#pragma unroll
      for (int ni = 0; ni < 4; ++ni) {
        const int col = inn0 + ni * 16 + l15;
        const int hd = col >> 6, dh = col & 63;
#pragma unroll
        for (int rr = 0; rr < 4; ++rr) {
          const int row = m0 + wm * 64 + mi * 16 + grp * 4 + rr;
          const int b = row >> 12, s = row & 4095;
          base[((size_t)(b * 12 + hd) * 4096 + s) * 64 + dh] = f2bf(acc[mi][ni][rr] * scl);
        }
      }
  } else if (MODE == 1) {
#pragma unroll
    for (int mi = 0; mi < 4; ++mi)
#pragma unroll
      for (int rr = 0; rr < 4; ++rr) {
        const int row = m0 + wm * 64 + mi * 16 + grp * 4 + rr;
#pragma unroll
        for (int ni = 0; ni < 4; ++ni) {
          const int col = n0 + wn * 64 + ni * 16 + l15;
          outF[(size_t)row * 768 + col] = acc[mi][ni][rr];
        }
      }
  } else {  // MODE 2: qg compact
    u16* __restrict__ base = outs.p[0];
#pragma unroll
    for (int mi = 0; mi < 4; ++mi)
#pragma unroll
      for (int ni = 0; ni < 4; ++ni) {
        const int col = n0 + wn * 64 + ni * 16 + l15;
        const int hd = col >> 6, dh = col & 63;
#pragma unroll
        for (int rr = 0; rr < 4; ++rr) {
          const int row = wm * 64 + mi * 16 + grp * 4 + rr;   // 0..127
          const int b = row >> 6, g = row & 63;
          base[((size_t)(b * 12 + hd) * 64 + g) * 64 + dh] = f2bf(acc[mi][ni][rr] * 0.125f * LOG2E);
        }
      }
  }
}

// ---------------------------------------------------------------------------
// (B,H,S,DH) -> (B,H,DH,S) bf16, two buffers (v->vT, vg->vgT)
__global__ __launch_bounds__(256) void transp_kernel(const u16* __restrict__ in0, u16* __restrict__ out0,
                                                     const u16* __restrict__ in1, u16* __restrict__ out1) {
  const u16* src = blockIdx.y ? in1 : in0;
  u16* dst = blockIdx.y ? out1 : out0;
  const int bh = blockIdx.x >> 6;
  const int s0 = (blockIdx.x & 63) << 6;
  __shared__ u16 tile[64][80];
  const int t = threadIdx.x;
  {
    const int sl = t >> 2, d0 = (t & 3) * 16;
    const u16* p = src + ((size_t)bh * 4096 + s0 + sl) * 64 + d0;
    *(short8x*)&tile[sl][d0] = *(const short8x*)p;
    *(short8x*)&tile[sl][d0 + 8] = *(const short8x*)(p + 8);
  }
  __syncthreads();
  {
    const int dh = t >> 2, q0 = (t & 3) * 16;
    short8x v0, v1;
#pragma unroll
    for (int j = 0; j < 8; ++j) {
      v0[j] = (short)tile[q0 + j][dh];
      v1[j] = (short)tile[q0 + 8 + j][dh];
    }
    u16* o = dst + ((size_t)bh * 64 + dh) * 4096 + s0 + q0;
    *(short8x*)o = v0;
    *(short8x*)(o + 8) = v1;
  }
}

// ---------------------------------------------------------------------------
// Gather K rows at clss -> kcls; v rows at clss transposed -> vtcls.
__global__ __launch_bounds__(256) void gcls_kernel(const u16* __restrict__ kB, const u16* __restrict__ vB,
                                                   const int* __restrict__ clss,
                                                   u16* __restrict__ kcls, u16* __restrict__ vtcls) {
  const int bh = blockIdx.x;
  __shared__ u16 tile[64][80];
  const int t = threadIdx.x;
  {
    const int g = t >> 2, d0 = (t & 3) * 16;
    const int row = clss[g];
    const u16* pk = kB + ((size_t)bh * 4096 + row) * 64 + d0;
    u16* ok = kcls + ((size_t)bh * 64 + g) * 64 + d0;
    *(short8x*)ok = *(const short8x*)pk;
    *(short8x*)(ok + 8) = *(const short8x*)(pk + 8);
    const u16* pv = vB + ((size_t)bh * 4096 + row) * 64 + d0;
    *(short8x*)&tile[g][d0] = *(const short8x*)pv;
    *(short8x*)&tile[g][d0 + 8] = *(const short8x*)(pv + 8);
  }
  __syncthreads();
  {
    const int dh = t >> 2, g0 = (t & 3) * 16;
    short8x v0, v1;
#pragma unroll
    for (int j = 0; j < 8; ++j) {
      v0[j] = (short)tile[g0 + j][dh];
      v1[j] = (short)tile[g0 + 8 + j][dh];
    }
    u16* o = vtcls + ((size_t)bh * 64 + dh) * 64 + g0;
    *(short8x*)o = v0;
    *(short8x*)(o + 8) = v1;
  }
}

// ---------------------------------------------------------------------------
// Swapped-operand 32x32 attention tile (m214/T12 structure, no LDS, no barriers).
// Wave = 32 queries (q = q0 + l31). One call = 64 keys (2 subtiles of 32).
// QK: mfma(K,Q) -> lane holds 16 scores per subtile for its q (rows=keys).
// Softmax in-register (1 shfl_xor(32) per reduce). P->bf16 via cvt_pk +
// permlane32_swap -> PV B-fragment directly. PV: mfma(V^T,P) -> acc = out^T.
struct AttnState {
  f32x16 a0, a1;   // out^T accumulators for dh-tiles 0,1
  float m, l;
};

DEV void attn_tile64(const u16* __restrict__ kp, const u16* __restrict__ vp, int vstr,
                     u32 vm0, u32 vm1, const short8x* qf, AttnState& S, int l31, int h8) {
  const f32x16 z16 = {0.f};
  f32x16 s0 = z16, s1 = z16;
  const u16* kr0 = kp + (size_t)l31 * 64 + h8;
  const u16* kr1 = kr0 + 32 * 64;
#pragma unroll
  for (int ks = 0; ks < 4; ++ks) {
    const short8x kf0 = *(const short8x*)(kr0 + ks * 16);
    const short8x kf1 = *(const short8x*)(kr1 + ks * 16);
    s0 = __builtin_amdgcn_mfma_f32_32x32x16_bf16(kf0, qf[ks], s0, 0, 0, 0);
    s1 = __builtin_amdgcn_mfma_f32_32x32x16_bf16(kf1, qf[ks], s1, 0, 0, 0);
  }
  // tile max (unmasked: shift-invariant softmax, all scores same scale)
  float mv = fmaxf(s0[0], s1[0]);
#pragma unroll
  for (int e = 1; e < 16; ++e) mv = fmaxf(mv, fmaxf(s0[e], s1[e]));
  mv = fmaxf(mv, __shfl_xor(mv, 32));
  // defer-max (THR=8 in log2 units)
  if (!__all(mv <= S.m + 8.f)) {
    const float mn = fmaxf(S.m, mv);
    const float sc = ex2(S.m - mn);
    S.m = mn;
    S.l *= sc;
#pragma unroll
    for (int e = 0; e < 16; ++e) { S.a0[e] *= sc; S.a1[e] *= sc; }
  }
  const int h4 = h8 >> 1;
  const u32 w0 = vm0 >> h4, w1 = vm1 >> h4;
  float p0[16], p1[16];
  float ls = 0.f;
#pragma unroll
  for (int e = 0; e < 16; ++e) {
    const int cr = (e & 3) + 8 * (e >> 2);
    const float b0 = (float)((w0 >> cr) & 1u);
    const float b1 = (float)((w1 >> cr) & 1u);
    const float v0 = ex2(s0[e] - S.m) * b0;
    const float v1 = ex2(s1[e] - S.m) * b1;
    p0[e] = v0; p1[e] = v1;
    ls += v0 + v1;
  }
  ls += __shfl_xor(ls, 32);
  S.l += ls;
  // pack pairs to bf16, permlane-swap across halves -> PV B-frags; PV MFMA
#pragma unroll
  for (int st = 0; st < 2; ++st) {
    const float* pp = st ? p1 : p0;
#pragma unroll
    for (int c = 0; c < 2; ++c) {
      u32 A1 = cvtpk_bf16(pp[8 * c + 0], pp[8 * c + 1]);
      u32 A2 = cvtpk_bf16(pp[8 * c + 2], pp[8 * c + 3]);
      u32 B1 = cvtpk_bf16(pp[8 * c + 4], pp[8 * c + 5]);
      u32 B2 = cvtpk_bf16(pp[8 * c + 6], pp[8 * c + 7]);
      plswap(A1, B1);
      plswap(A2, B2);
      union { u32 w[4]; short8x v; } u;
      u.w[0] = A1; u.w[1] = A2; u.w[2] = B1; u.w[3] = B2;
      const int sc4 = st * 2 + c;
      const u16* vr = vp + sc4 * 16 + h8;
      const short8x vf0 = *(const short8x*)(vr + (size_t)l31 * vstr);
      const short8x vf1 = *(const short8x*)(vr + (size_t)(32 + l31) * vstr);
      S.a0 = __builtin_amdgcn_mfma_f32_32x32x16_bf16(vf0, u.v, S.a0, 0, 0, 0);
      S.a1 = __builtin_amdgcn_mfma_f32_32x32x16_bf16(vf1, u.v, S.a1, 0, 0, 0);
    }
  }
}

DEV u32 bandmask32(int q, int kb2) {
  const int lo = imax(q - 256 - kb2, 0);
  const int hi = imin(q + 256 - kb2, 31);
  if (hi < lo) return 0u;
  return (0xFFFFFFFFu << lo) & (0xFFFFFFFFu >> (31 - hi));
}

// ---------------------------------------------------------------------------
// Fused attention: blocks 0..95 = global-token partials (wave = (bh,qsub,slice));
// blocks 96..863 = band (wave = 32 queries, ~9 band tiles + clss tile).
struct FusedArgs {
  const u16 *qB, *kB, *vT, *kcls, *vtcls, *qgc, *kgB, *vgT;
  const u32 *kv32, *mv32, *mc32;
  u16* aout;
  float *pm, *pl, *pacc;
};

__global__ __launch_bounds__(256, 3) void band_kernel(FusedArgs a) {
  const int t = threadIdx.x;
  const int w = t >> 6, l = t & 63;
  const int l31 = l & 31, hf = l >> 5, h8 = hf * 8, h4 = hf * 4;
  const f32x16 z16 = {0.f};

  if (blockIdx.x < 96) {
    // ---- global-token attention partial ----
    const int wid = blockIdx.x * 4 + w;     // 384 waves
    const int sl = wid & 7;
    const int qsub = (wid >> 3) & 1;
    const int bh = wid >> 4;
    const int b = bh / 12;
    const int q = qsub * 32 + l31;

    const u16* kgb = a.kgB + (size_t)bh * 4096 * 64;
    const u16* vgb = a.vgT + (size_t)bh * 64 * 4096;
    short8x qf[4];
#pragma unroll
    for (int ks = 0; ks < 4; ++ks)
      qf[ks] = *(const short8x*)(a.qgc + ((size_t)bh * 64 + q) * 64 + ks * 16 + h8);

    AttnState S;
    S.a0 = z16; S.a1 = z16; S.m = -60.f; S.l = 0.f;
    for (int tt = sl * 8; tt < sl * 8 + 8; ++tt) {
      const int kb = tt * 64;
      const u32 vm0 = a.mv32[b * 128 + tt * 2];
      const u32 vm1 = a.mv32[b * 128 + tt * 2 + 1];
      attn_tile64(kgb + (size_t)kb * 64, vgb + kb, 4096, vm0, vm1, qf, S, l31, h8);
    }
    const int pbase = (bh * 8 + sl) * 64;
    float* pr = a.pacc + ((size_t)pbase + q) * 64;
#pragma unroll
    for (int rq = 0; rq < 4; ++rq) {
      f32x4 v0 = {S.a0[rq * 4 + 0], S.a0[rq * 4 + 1], S.a0[rq * 4 + 2], S.a0[rq * 4 + 3]};
      f32x4 v1 = {S.a1[rq * 4 + 0], S.a1[rq * 4 + 1], S.a1[rq * 4 + 2], S.a1[rq * 4 + 3]};
      *(f32x4*)(pr + rq * 8 + h4) = v0;
      *(f32x4*)(pr + 32 + rq * 8 + h4) = v1;
    }
    if (hf == 0) {
      a.pm[pbase + q] = S.m;
      a.pl[pbase + q] = S.l;
    }
    return;
  }

  // ---- band path ----
  int bid = blockIdx.x - 96;
  bid = (bid & 7) * 96 + (bid >> 3);   // XCD chunking (768 = 8 * 96, bijective)
  const int qblk = bid & 31;
  const int h = (bid >> 5) % 12;
  const int b = bid / 384;
  const int bh = b * 12 + h;
  const int q0 = qblk * 128 + w * 32;
  const int q = q0 + l31;

  const u16* kbh = a.kB + (size_t)bh * 4096 * 64;
  const u16* vbh = a.vT + (size_t)bh * 64 * 4096;

  short8x qf[4];
#pragma unroll
  for (int ks = 0; ks < 4; ++ks)
    qf[ks] = *(const short8x*)(a.qB + ((size_t)bh * 4096 + q) * 64 + ks * 16 + h8);

  AttnState S;
  S.a0 = z16; S.a1 = z16; S.m = -60.f; S.l = 0.f;

  const int tlo = imax(0, q0 - 256) >> 6;
  const int thi = imin(63, (q0 + 287) >> 6);

  for (int tt = tlo; tt <= thi; ++tt) {
    const int kb = tt * 64;
    u32 vm0 = a.kv32[b * 128 + tt * 2];
    u32 vm1 = a.kv32[b * 128 + tt * 2 + 1];
    const int d0 = kb - q0, d1 = kb + 32 - q0;
    if (d0 < -225 || d0 > 225) vm0 &= bandmask32(q, kb);
    if (d1 < -225 || d1 > 225) vm1 &= bandmask32(q, kb + 32);
    attn_tile64(kbh + (size_t)kb * 64, vbh + kb, 4096, vm0, vm1, qf, S, l31, h8);
  }
  // clss (global-key) tile
  attn_tile64(a.kcls + (size_t)bh * 4096, a.vtcls + (size_t)bh * 4096, 64,
              a.mc32[b * 2], a.mc32[b * 2 + 1], qf, S, l31, h8);

  // finalize: out = acc/l, store (B,S,D) bf16 (lane q owns row q)
  const float inv = 1.f / S.l;
  u16* ob = a.aout + ((size_t)b * 4096 + q) * 768 + h * 64;
#pragma unroll
  for (int rq = 0; rq < 4; ++rq) {
    union { u16 s[4]; uint2 v; } o0, o1;
#pragma unroll
    for (int j = 0; j < 4; ++j) {
      o0.s[j] = f2bf(S.a0[rq * 4 + j] * inv);
      o1.s[j] = f2bf(S.a1[rq * 4 + j] * inv);
    }
    *(uint2*)(ob + rq * 8 + h4) = o0.v;
    *(uint2*)(ob + 32 + rq * 8 + h4) = o1.v;
  }
}

// ---------------------------------------------------------------------------
// Global-token attention merge: combine 8 key-slice partials into clss rows of aout.
__global__ __launch_bounds__(256) void ogm_kernel(const float* __restrict__ pm, const float* __restrict__ pl,
                                                  const float* __restrict__ pacc, const int* __restrict__ clss,
                                                  u16* __restrict__ aout) {
  const int bh = blockIdx.x;
  const int b = bh / 12, h = bh % 12;
  const int t = threadIdx.x;
  const int r = t >> 2, cs = (t & 3) * 16;
  float mv[8];
  float M = -1e30f;
#pragma unroll
  for (int s = 0; s < 8; ++s) {
    mv[s] = pm[(bh * 8 + s) * 64 + r];
    M = fmaxf(M, mv[s]);
  }
  float L = 0.f, f[8];
#pragma unroll
  for (int s = 0; s < 8; ++s) {
    f[s] = ex2(mv[s] - M);
    L += pl[(bh * 8 + s) * 64 + r] * f[s];
  }
  float o[16];
#pragma unroll
  for (int j = 0; j < 16; ++j) o[j] = 0.f;
#pragma unroll
  for (int s = 0; s < 8; ++s) {
    const float* pr = pacc + (size_t)(bh * 8 + s) * 4096 + r * 64 + cs;
#pragma unroll
    for (int j4 = 0; j4 < 4; ++j4) {
      const float4 a = *(const float4*)(pr + j4 * 4);
      o[j4 * 4 + 0] += a.x * f[s];
      o[j4 * 4 + 1] += a.y * f[s];
      o[j4 * 4 + 2] += a.z * f[s];
      o[j4 * 4 + 3] += a.w * f[s];
    }
  }
  const float inv = 1.f / L;
  short8x v0, v1;
#pragma unroll
  for (int j = 0; j < 8; ++j) {
    v0[j] = (short)f2bf(o[j] * inv);
    v1[j] = (short)f2bf(o[8 + j] * inv);
  }
  u16* op = aout + ((size_t)b * 4096 + clss[r]) * 768 + h * 64 + cs;
  *(short8x*)op = v0;
  *(short8x*)(op + 8) = v1;
}

// ---------------------------------------------------------------------------
extern "C" void kernel_launch(void* const* d_in, const int* in_sizes, int n_in,
                              void* d_out, int out_size, void* d_ws, size_t ws_size,
                              hipStream_t stream) {
  (void)in_sizes; (void)n_in; (void)out_size; (void)ws_size;
  const int* x = (const int*)d_in[0];
  const int* mask = (const int*)d_in[1];
  const int* clss = (const int*)d_in[2];
  const float* emb = (const float*)d_in[3];
  const float* pos = (const float*)d_in[4];
  const float* wq = (const float*)d_in[5];
  const float* wk = (const float*)d_in[6];
  const float* wv = (const float*)d_in[7];
  const float* wo = (const float*)d_in[8];
  const float* wqg = (const float*)d_in[9];
  const float* wkg = (const float*)d_in[10];
  const float* wvg = (const float*)d_in[11];
  float* out = (float*)d_out;

  char* ws = (char*)d_ws;
  size_t off = 0;
  auto alloc = [&](size_t n) { char* p = ws + off; off = (off + n + 255) & ~(size_t)255; return p; };
  const size_t SZ = (size_t)2 * 12 * 4096 * 64 * 2;  // one (B,H,S,DH) bf16 buffer
  u16* hb = (u16*)alloc(SZ);
  u16* wt = (u16*)alloc((size_t)7 * 768 * 768 * 2);
  u16* qb = (u16*)alloc(SZ);
  u16* kb = (u16*)alloc(SZ);
  u16* vb = (u16*)alloc(SZ);
  u16* kgb = (u16*)alloc(SZ);
  u16* vgb = (u16*)alloc(SZ);
  u16* vts = (u16*)alloc(SZ);
  u16* vgts = (u16*)alloc(SZ);
  u16* hg = (u16*)alloc((size_t)128 * 768 * 2);
  u16* qgc = (u16*)alloc((size_t)24 * 64 * 64 * 2);
  u16* kcls = (u16*)alloc((size_t)24 * 64 * 64 * 2);
  u16* vtcls = (u16*)alloc((size_t)24 * 64 * 64 * 2);
  u32* kv32 = (u32*)alloc(256 * 4);
  u32* mv32 = (u32*)alloc(256 * 4);
  u32* mc32 = (u32*)alloc(4 * 4);
  u16* aout = (u16*)alloc(SZ);
  float* pm = (float*)alloc((size_t)192 * 64 * 4);
  float* pl = (float*)alloc((size_t)192 * 64 * 4);
  float* pacc = (float*)alloc((size_t)192 * 4096 * 4);

  WPtrs wp;
  wp.p[0] = wq; wp.p[1] = wk; wp.p[2] = wv; wp.p[3] = wkg; wp.p[4] = wvg; wp.p[5] = wqg; wp.p[6] = wo;

  wconv_kernel<<<dim3(144, 7), 256, 0, stream>>>(wp, wt);
  embed_kernel<<<2048, 256, 0, stream>>>(x, emb, pos, hb);
  bits_kernel<<<1, 256, 0, stream>>>(clss, mask, kv32, mv32, mc32);

  Outs6 o5;
  o5.p[0] = qb; o5.p[1] = kb; o5.p[2] = vb; o5.p[3] = kgb; o5.p[4] = vgb; o5.p[5] = nullptr;
  gemm_kernel<0><<<dim3(30, 64), 256, 0, stream>>>(hb, wt, o5, nullptr);

  hgather_kernel<<<48, 256, 0, stream>>>(hb, clss, hg);
  Outs6 oq = {};
  oq.p[0] = qgc;
  gemm_kernel<2><<<dim3(6, 1), 256, 0, stream>>>(hg, wt + (size_t)5 * 768 * 768, oq, nullptr);

  transp_kernel<<<dim3(1536, 2), 256, 0, stream>>>(vb, vts, vgb, vgts);
  gcls_kernel<<<24, 256, 0, stream>>>(kb, vb, clss, kcls, vtcls);

  FusedArgs fa;
  fa.qB = qb; fa.kB = kb; fa.vT = vts; fa.kcls = kcls; fa.vtcls = vtcls;
  fa.qgc = qgc; fa.kgB = kgb; fa.vgT = vgts;
  fa.kv32 = kv32; fa.mv32 = mv32; fa.mc32 = mc32;
  fa.aout = aout; fa.pm = pm; fa.pl = pl; fa.pacc = pacc;
  band_kernel<<<864, 256, 0, stream>>>(fa);

  ogm_kernel<<<24, 256, 0, stream>>>(pm, pl, pacc, clss, aout);

  Outs6 dummy = {};
  gemm_kernel<1><<<dim3(6, 64), 256, 0, stream>>>(aout, wt + (size_t)6 * 768 * 768, dummy, out);
}